// Round 1
// baseline (6451.811 us; speedup 1.0000x reference)
//
#include <hip/hip_runtime.h>
#include <math.h>

typedef unsigned short u16;
typedef unsigned int u32;
typedef short bf16x8 __attribute__((ext_vector_type(8)));
typedef float f32x4 __attribute__((ext_vector_type(4)));

__device__ __forceinline__ float bf2f(u16 b) {
    u32 x = ((u32)b) << 16;
    return __builtin_bit_cast(float, x);
}
__device__ __forceinline__ u16 f2bf(float f) {
    u32 u = __builtin_bit_cast(u32, f);
    u32 r = (u + 0x7fffu + ((u >> 16) & 1u)) >> 16;  // RNE
    return (u16)r;
}
__device__ __forceinline__ float wave_red_sum(float v) {
#pragma unroll
    for (int o = 32; o; o >>= 1) v += __shfl_down(v, o, 64);
    return v;
}
__device__ __forceinline__ float wave_red_max(float v) {
#pragma unroll
    for (int o = 32; o; o >>= 1) v = fmaxf(v, __shfl_down(v, o, 64));
    return v;
}

// ---------------- elementwise helpers ----------------

__global__ void convert_kernel(const float* __restrict__ in, u16* __restrict__ out, int n) {
    for (int i = blockIdx.x * 256 + threadIdx.x; i < n; i += gridDim.x * 256)
        out[i] = f2bf(in[i]);
}

__global__ void copy_kernel(const float* __restrict__ in, float* __restrict__ out, int n) {
    for (int i = blockIdx.x * 256 + threadIdx.x; i < n; i += gridDim.x * 256)
        out[i] = in[i];
}

// LN (no affine): x fp32 (4096,768) -> h bf16
__global__ __launch_bounds__(256) void ln_plain(const float* __restrict__ x, u16* __restrict__ h) {
    int m = blockIdx.x, t = threadIdx.x;
    const float* row = x + (size_t)m * 768;
    float v0 = row[t], v1 = row[t + 256], v2 = row[t + 512];
    __shared__ float red[4];
    float s = wave_red_sum(v0 + v1 + v2);
    if ((t & 63) == 0) red[t >> 6] = s;
    __syncthreads();
    float mean = (red[0] + red[1] + red[2] + red[3]) * (1.f / 768.f);
    __syncthreads();
    float d0 = v0 - mean, d1 = v1 - mean, d2 = v2 - mean;
    float q = wave_red_sum(d0 * d0 + d1 * d1 + d2 * d2);
    if ((t & 63) == 0) red[t >> 6] = q;
    __syncthreads();
    float inv = rsqrtf((red[0] + red[1] + red[2] + red[3]) * (1.f / 768.f) + 1e-7f);
    u16* hr = h + (size_t)m * 768;
    hr[t] = f2bf(d0 * inv);
    hr[t + 256] = f2bf(d1 * inv);
    hr[t + 512] = f2bf(d2 * inv);
}

// x += LN(c)*g + b
__global__ __launch_bounds__(256) void ln_res(const float* __restrict__ c, const float* __restrict__ g,
                                              const float* __restrict__ bb, float* __restrict__ x) {
    int m = blockIdx.x, t = threadIdx.x;
    const float* row = c + (size_t)m * 768;
    float v0 = row[t], v1 = row[t + 256], v2 = row[t + 512];
    __shared__ float red[4];
    float s = wave_red_sum(v0 + v1 + v2);
    if ((t & 63) == 0) red[t >> 6] = s;
    __syncthreads();
    float mean = (red[0] + red[1] + red[2] + red[3]) * (1.f / 768.f);
    __syncthreads();
    float d0 = v0 - mean, d1 = v1 - mean, d2 = v2 - mean;
    float q = wave_red_sum(d0 * d0 + d1 * d1 + d2 * d2);
    if ((t & 63) == 0) red[t >> 6] = q;
    __syncthreads();
    float inv = rsqrtf((red[0] + red[1] + red[2] + red[3]) * (1.f / 768.f) + 1e-7f);
    float* xr = x + (size_t)m * 768;
    xr[t] += d0 * inv * g[t] + bb[t];
    xr[t + 256] += d1 * inv * g[t + 256] + bb[t + 256];
    xr[t + 512] += d2 * inv * g[t + 512] + bb[t + 512];
}

// u (4096,4096) bf16: glu = a * gelu_tanh(gate); LN over 2048; -> h2 bf16 (4096,2048)
__global__ __launch_bounds__(256) void glu_ln(const u16* __restrict__ u, u16* __restrict__ h2) {
    int m = blockIdx.x, t = threadIdx.x;
    const u16* row = u + (size_t)m * 4096;
    float gv[8];
    float s = 0.f;
#pragma unroll
    for (int jj = 0; jj < 8; jj++) {
        int j = jj * 256 + t;
        float a = bf2f(row[j]);
        float gt = bf2f(row[2048 + j]);
        float ge = 0.5f * gt * (1.f + tanhf(0.7978845608028654f * (gt + 0.044715f * gt * gt * gt)));
        gv[jj] = a * ge;
        s += gv[jj];
    }
    __shared__ float red[4];
    s = wave_red_sum(s);
    if ((t & 63) == 0) red[t >> 6] = s;
    __syncthreads();
    float mean = (red[0] + red[1] + red[2] + red[3]) * (1.f / 2048.f);
    __syncthreads();
    float q2 = 0.f;
#pragma unroll
    for (int jj = 0; jj < 8; jj++) {
        float d = gv[jj] - mean;
        q2 += d * d;
    }
    q2 = wave_red_sum(q2);
    if ((t & 63) == 0) red[t >> 6] = q2;
    __syncthreads();
    float inv = rsqrtf((red[0] + red[1] + red[2] + red[3]) * (1.f / 2048.f) + 1e-7f);
    u16* out = h2 + (size_t)m * 2048;
#pragma unroll
    for (int jj = 0; jj < 8; jj++) out[jj * 256 + t] = f2bf((gv[jj] - mean) * inv);
}

// ---------------- GEMM: C[m,n] = sum_k A[m,k]*B[n,k] (+bias), bf16 MFMA ----------------
// modes: 0 = fp32 out, 1 = bf16 out, 2 = qk scatter (out0=q,out1=k), 3 = v scatter, 4 = fp32 residual +=
__global__ __launch_bounds__(256) void gemm_nt(const u16* __restrict__ A, const u16* __restrict__ B,
                                               const float* __restrict__ bias, int M, int N, int K,
                                               int mode, void* __restrict__ out0, void* __restrict__ out1) {
    __shared__ __align__(16) u16 As[128 * 72];
    __shared__ __align__(16) u16 Bs[128 * 72];
    const int t = threadIdx.x;
    const int lane = t & 63, wave = t >> 6;
    const int wm = (wave >> 1) * 64, wn = (wave & 1) * 64;
    const int fr = lane & 15, qd = lane >> 4;
    const int m0 = blockIdx.y * 128, n0 = blockIdx.x * 128;
    const int row_s = t >> 3, g_s = t & 7;

    f32x4 zero4 = {0.f, 0.f, 0.f, 0.f};
    f32x4 acc[4][4];
#pragma unroll
    for (int i = 0; i < 4; i++)
#pragma unroll
        for (int j = 0; j < 4; j++) acc[i][j] = zero4;

    for (int k0 = 0; k0 < K; k0 += 64) {
        __syncthreads();
#pragma unroll
        for (int it = 0; it < 4; ++it) {
            int row = it * 32 + row_s;
            const float4* src = (const float4*)(A + (size_t)(m0 + row) * K + k0 + g_s * 8);
            *(float4*)&As[row * 72 + g_s * 8] = *src;
        }
#pragma unroll
        for (int it = 0; it < 4; ++it) {
            int row = it * 32 + row_s;
            const float4* src = (const float4*)(B + (size_t)(n0 + row) * K + k0 + g_s * 8);
            *(float4*)&Bs[row * 72 + g_s * 8] = *src;
        }
        __syncthreads();
#pragma unroll
        for (int s = 0; s < 2; ++s) {
            bf16x8 aF[4], bF[4];
#pragma unroll
            for (int i = 0; i < 4; i++) aF[i] = *(const bf16x8*)&As[(wm + i * 16 + fr) * 72 + s * 32 + qd * 8];
#pragma unroll
            for (int j = 0; j < 4; j++) bF[j] = *(const bf16x8*)&Bs[(wn + j * 16 + fr) * 72 + s * 32 + qd * 8];
#pragma unroll
            for (int i = 0; i < 4; i++)
#pragma unroll
                for (int j = 0; j < 4; j++)
                    acc[i][j] = __builtin_amdgcn_mfma_f32_16x16x32_bf16(aF[i], bF[j], acc[i][j], 0, 0, 0);
        }
    }

    // epilogue: D col = lane&15, row = (lane>>4)*4 + reg
#pragma unroll
    for (int j = 0; j < 4; j++) {
        int nn = n0 + wn + j * 16 + fr;
        float bval = bias ? bias[nn] : 0.f;
#pragma unroll
        for (int i = 0; i < 4; i++) {
#pragma unroll
            for (int rg = 0; rg < 4; ++rg) {
                int mm = m0 + wm + i * 16 + qd * 4 + rg;
                float val = acc[i][j][rg] + bval;
                if (mode == 0) {
                    ((float*)out0)[(size_t)mm * N + nn] = val;
                } else if (mode == 1) {
                    ((u16*)out0)[(size_t)mm * N + nn] = f2bf(val);
                } else if (mode == 2) {
                    int sidx = mm >> 3, bidx = mm & 7;
                    int nn2 = nn;
                    u16* dst = (u16*)out0;
                    if (nn2 >= 768) { dst = (u16*)out1; nn2 -= 768; }
                    int hh = nn2 >> 6, dd = nn2 & 63;
                    dst[(size_t)((bidx * 12 + hh) * 512 + sidx) * 64 + dd] = f2bf(val);
                } else if (mode == 3) {
                    int sidx = mm >> 3, bidx = mm & 7;
                    int hh = nn >> 6, dd = nn & 63;
                    ((u16*)out0)[(size_t)((bidx * 12 + hh) * 512 + sidx) * 64 + dd] = f2bf(val);
                } else {
                    ((float*)out0)[(size_t)mm * N + nn] += val;
                }
            }
        }
    }
}

// ---------------- position / attention ----------------

// pos[j,n] = rel[j,:] . Wqk[n,:] + bqk[n];  split into qpos/kpos bf16 (head,bucket,d)
__global__ __launch_bounds__(256) void pos_kernel(const float* __restrict__ rel, const u16* __restrict__ wqk,
                                                  const float* __restrict__ bqk, u16* __restrict__ qposb,
                                                  u16* __restrict__ kposb) {
    int j = blockIdx.x, t = threadIdx.x;
    __shared__ float r[768];
    for (int i = t; i < 768; i += 256) r[i] = rel[(size_t)j * 768 + i];
    __syncthreads();
    for (int n = t; n < 1536; n += 256) {
        const u32* w32 = (const u32*)(wqk + (size_t)n * 768);
        float sum = bqk[n];
        for (int i = 0; i < 384; i++) {
            u32 u = w32[i];
            float lo = __builtin_bit_cast(float, u << 16);
            float hi = __builtin_bit_cast(float, u & 0xffff0000u);
            sum = fmaf(lo, r[2 * i], sum);
            sum = fmaf(hi, r[2 * i + 1], sum);
        }
        int hh = n >> 7, wd = n & 127;
        if (wd < 64) qposb[(size_t)(hh * 63 + j) * 64 + wd] = f2bf(sum);
        else kposb[(size_t)(hh * 63 + j) * 64 + (wd - 64)] = f2bf(sum);
    }
}

// c2p[bh,s,j] = q[bh,s,:].kpos[h,j,:];  p2c[bh,s,j] = k[bh,s,:].qpos[h,j,:]
__global__ __launch_bounds__(64) void c2p_p2c_kernel(const u16* __restrict__ qbuf, const u16* __restrict__ kbuf,
                                                     const u16* __restrict__ qposb, const u16* __restrict__ kposb,
                                                     float* __restrict__ c2p, float* __restrict__ p2c) {
    int t = threadIdx.x;
    int sidx = blockIdx.x, bh = blockIdx.y, h = bh % 12;
    __shared__ float qr[64], kr[64];
    size_t base = (size_t)(bh * 512 + sidx) * 64;
    qr[t] = bf2f(qbuf[base + t]);
    kr[t] = bf2f(kbuf[base + t]);
    __syncthreads();
    float sc = 0.f, sp = 0.f;
    if (t < 63) {
        const u16* kp = kposb + (size_t)(h * 63 + t) * 64;
        const u16* qp = qposb + (size_t)(h * 63 + t) * 64;
        for (int d = 0; d < 64; d++) {
            sc = fmaf(qr[d], bf2f(kp[d]), sc);
            sp = fmaf(kr[d], bf2f(qp[d]), sp);
        }
    }
    c2p[base + t] = (t < 63) ? sc : 0.f;
    p2c[base + t] = (t < 63) ? sp : 0.f;
}

// fused scores + softmax + PV, one block per (bh, q)
__global__ __launch_bounds__(512) void attn_kernel(const u16* __restrict__ qbuf, const u16* __restrict__ kbuf,
                                                   const u16* __restrict__ vbuf, const float* __restrict__ c2p,
                                                   const float* __restrict__ p2c, const int* __restrict__ posidx,
                                                   const unsigned char* __restrict__ mask, u16* __restrict__ ctxb) {
    __shared__ float qlds[64], c2pl[64], pr[512], pv[512], red[8];
    int t = threadIdx.x;
    int q = blockIdx.x, bh = blockIdx.y;
    int b = bh / 12, h = bh % 12;
    if (t < 64) qlds[t] = bf2f(qbuf[(size_t)(bh * 512 + q) * 64 + t]);
    else if (t < 128) c2pl[t - 64] = c2p[(size_t)(bh * 512 + q) * 64 + (t - 64)];
    __syncthreads();
    int k = t;
    const u32* kp = (const u32*)(kbuf + (size_t)(bh * 512 + k) * 64);
    float dot = 0.f;
#pragma unroll
    for (int i = 0; i < 32; i++) {
        u32 u = kp[i];
        float lo = __builtin_bit_cast(float, u << 16);
        float hi = __builtin_bit_cast(float, u & 0xffff0000u);
        dot = fmaf(lo, qlds[2 * i], dot);
        dot = fmaf(hi, qlds[2 * i + 1], dot);
    }
    int idx = posidx[q * 512 + k];
    float s = 0.07216878364870323f * (dot + c2pl[idx] + p2c[(size_t)(bh * 512 + k) * 64 + idx]);
    bool mk = mask[b * 512 + k] != 0;
    if (mk) s = -1e30f;
    float v = wave_red_max(s);
    if ((t & 63) == 0) red[t >> 6] = v;
    __syncthreads();
    float mx = red[0];
#pragma unroll
    for (int i = 1; i < 8; i++) mx = fmaxf(mx, red[i]);
    __syncthreads();
    float e = mk ? 0.f : expf(s - mx);
    v = wave_red_sum(e);
    if ((t & 63) == 0) red[t >> 6] = v;
    __syncthreads();
    float sum = red[0] + red[1] + red[2] + red[3] + red[4] + red[5] + red[6] + red[7];
    pr[k] = e / sum;
    __syncthreads();
    int d = t & 63, kc = t >> 6;
    const u16* vp = vbuf + (size_t)(bh * 512 + kc * 64) * 64 + d;
    float a = 0.f;
#pragma unroll
    for (int kk = 0; kk < 64; kk++) a = fmaf(pr[kc * 64 + kk], bf2f(vp[(size_t)kk * 64]), a);
    pv[t] = a;
    __syncthreads();
    if (t < 64) {
        float c = 0.f;
#pragma unroll
        for (int i = 0; i < 8; i++) c += pv[i * 64 + t];
        int m = q * 8 + b;
        ctxb[(size_t)m * 768 + h * 64 + t] = f2bf(c);
    }
}

// ---------------- host ----------------

extern "C" void kernel_launch(void* const* d_in, const int* in_sizes, int n_in, void* d_out, int out_size,
                              void* d_ws, size_t ws_size, hipStream_t stream) {
    const float* hidden = (const float*)d_in[0];
    const unsigned char* mask = (const unsigned char*)d_in[1];
    const float* relemb = (const float*)d_in[2];
    const float* Wqk = (const float*)d_in[3];
    const float* bqk = (const float*)d_in[4];
    const float* Wv = (const float*)d_in[5];
    const float* bv = (const float*)d_in[6];
    const float* Wo = (const float*)d_in[7];
    const float* bo = (const float*)d_in[8];
    const float* lng = (const float*)d_in[9];
    const float* lnb = (const float*)d_in[10];
    const float* W1 = (const float*)d_in[11];
    const float* W2 = (const float*)d_in[12];
    const int* posidx = (const int*)d_in[13];
    float* x = (float*)d_out;

    char* wsp = (char*)d_ws;
    auto alloc = [&](size_t bytes) -> char* {
        char* p = wsp;
        wsp += (bytes + 255) & ~(size_t)255;
        return p;
    };
    u16* wqk_bf = (u16*)alloc(6ull * 1536 * 768 * 2);
    u16* wv_bf = (u16*)alloc(6ull * 768 * 768 * 2);
    u16* wo_bf = (u16*)alloc(6ull * 768 * 768 * 2);
    u16* w1_bf = (u16*)alloc(6ull * 4096 * 768 * 2);
    u16* w2_bf = (u16*)alloc(6ull * 768 * 2048 * 2);
    u16* h_bf = (u16*)alloc(4096ull * 768 * 2);
    u16* qb = (u16*)alloc(96ull * 512 * 64 * 2);
    u16* kb = (u16*)alloc(96ull * 512 * 64 * 2);
    u16* vb = (u16*)alloc(96ull * 512 * 64 * 2);
    u16* qposb = (u16*)alloc(12ull * 63 * 64 * 2);
    u16* kposb = (u16*)alloc(12ull * 63 * 64 * 2);
    float* c2p = (float*)alloc(96ull * 512 * 64 * 4);
    float* p2c = (float*)alloc(96ull * 512 * 64 * 4);
    u16* ctxb = (u16*)alloc(4096ull * 768 * 2);
    float* ctxproj = (float*)alloc(4096ull * 768 * 4);
    u16* ubuf = (u16*)alloc(4096ull * 4096 * 2);
    u16* h2 = (u16*)alloc(4096ull * 2048 * 2);
    (void)ws_size;
    (void)in_sizes;
    (void)n_in;
    (void)out_size;

    auto conv = [&](const float* in, u16* out, size_t n) {
        size_t blocks = (n + 255) / 256;
        if (blocks > 8192) blocks = 8192;
        convert_kernel<<<dim3((unsigned)blocks), dim3(256), 0, stream>>>(in, out, (int)n);
    };
    conv(Wqk, wqk_bf, 6ull * 1536 * 768);
    conv(Wv, wv_bf, 6ull * 768 * 768);
    conv(Wo, wo_bf, 6ull * 768 * 768);
    conv(W1, w1_bf, 6ull * 4096 * 768);
    conv(W2, w2_bf, 6ull * 768 * 2048);
    copy_kernel<<<dim3(4096), dim3(256), 0, stream>>>(hidden, x, 4096 * 768);

    for (int l = 0; l < 6; l++) {
        ln_plain<<<dim3(4096), dim3(256), 0, stream>>>(x, h_bf);
        gemm_nt<<<dim3(12, 32), dim3(256), 0, stream>>>(h_bf, wqk_bf + (size_t)l * 1536 * 768, bqk + l * 1536,
                                                        4096, 1536, 768, 2, qb, kb);
        gemm_nt<<<dim3(6, 32), dim3(256), 0, stream>>>(h_bf, wv_bf + (size_t)l * 768 * 768, bv + l * 768,
                                                       4096, 768, 768, 3, vb, nullptr);
        pos_kernel<<<dim3(63), dim3(256), 0, stream>>>(relemb, wqk_bf + (size_t)l * 1536 * 768, bqk + l * 1536,
                                                       qposb, kposb);
        c2p_p2c_kernel<<<dim3(512, 96), dim3(64), 0, stream>>>(qb, kb, qposb, kposb, c2p, p2c);
        attn_kernel<<<dim3(512, 96), dim3(512), 0, stream>>>(qb, kb, vb, c2p, p2c, posidx, mask, ctxb);
        gemm_nt<<<dim3(6, 32), dim3(256), 0, stream>>>(ctxb, wo_bf + (size_t)l * 768 * 768, bo + l * 768,
                                                       4096, 768, 768, 0, ctxproj, nullptr);
        ln_res<<<dim3(4096), dim3(256), 0, stream>>>(ctxproj, lng + l * 768, lnb + l * 768, x);
        ln_plain<<<dim3(4096), dim3(256), 0, stream>>>(x, h_bf);
        gemm_nt<<<dim3(32, 32), dim3(256), 0, stream>>>(h_bf, w1_bf + (size_t)l * 4096 * 768, nullptr,
                                                        4096, 4096, 768, 1, ubuf, nullptr);
        glu_ln<<<dim3(4096), dim3(256), 0, stream>>>(ubuf, h2);
        gemm_nt<<<dim3(6, 32), dim3(256), 0, stream>>>(h2, w2_bf + (size_t)l * 768 * 2048, nullptr,
                                                       4096, 768, 2048, 4, x, nullptr);
    }
}

// Round 2
// 2511.986 us; speedup vs baseline: 2.5684x; 2.5684x over previous
//
#include <hip/hip_runtime.h>
#include <math.h>

typedef unsigned short u16;
typedef unsigned int u32;
typedef short bf16x8 __attribute__((ext_vector_type(8)));
typedef float f32x4 __attribute__((ext_vector_type(4)));

__device__ __forceinline__ float bf2f(u16 b) {
    u32 x = ((u32)b) << 16;
    return __builtin_bit_cast(float, x);
}
__device__ __forceinline__ u16 f2bf(float f) {
    u32 u = __builtin_bit_cast(u32, f);
    u32 r = (u + 0x7fffu + ((u >> 16) & 1u)) >> 16;  // RNE
    return (u16)r;
}
__device__ __forceinline__ float wave_red_sum(float v) {
#pragma unroll
    for (int o = 32; o; o >>= 1) v += __shfl_down(v, o, 64);
    return v;
}

// ---------------- elementwise helpers ----------------

__global__ void convert_kernel(const float* __restrict__ in, u16* __restrict__ out, int n) {
    for (int i = blockIdx.x * 256 + threadIdx.x; i < n; i += gridDim.x * 256)
        out[i] = f2bf(in[i]);
}

__global__ void copy_kernel(const float* __restrict__ in, float* __restrict__ out, int n) {
    for (int i = blockIdx.x * 256 + threadIdx.x; i < n; i += gridDim.x * 256)
        out[i] = in[i];
}

// LN (no affine): x fp32 (4096,768) -> h bf16
__global__ __launch_bounds__(256) void ln_plain(const float* __restrict__ x, u16* __restrict__ h) {
    int m = blockIdx.x, t = threadIdx.x;
    const float* row = x + (size_t)m * 768;
    float v0 = row[t], v1 = row[t + 256], v2 = row[t + 512];
    __shared__ float red[4];
    float s = wave_red_sum(v0 + v1 + v2);
    if ((t & 63) == 0) red[t >> 6] = s;
    __syncthreads();
    float mean = (red[0] + red[1] + red[2] + red[3]) * (1.f / 768.f);
    __syncthreads();
    float d0 = v0 - mean, d1 = v1 - mean, d2 = v2 - mean;
    float q = wave_red_sum(d0 * d0 + d1 * d1 + d2 * d2);
    if ((t & 63) == 0) red[t >> 6] = q;
    __syncthreads();
    float inv = rsqrtf((red[0] + red[1] + red[2] + red[3]) * (1.f / 768.f) + 1e-7f);
    u16* hr = h + (size_t)m * 768;
    hr[t] = f2bf(d0 * inv);
    hr[t + 256] = f2bf(d1 * inv);
    hr[t + 512] = f2bf(d2 * inv);
}

// x += LN(c)*g + b
__global__ __launch_bounds__(256) void ln_res(const float* __restrict__ c, const float* __restrict__ g,
                                              const float* __restrict__ bb, float* __restrict__ x) {
    int m = blockIdx.x, t = threadIdx.x;
    const float* row = c + (size_t)m * 768;
    float v0 = row[t], v1 = row[t + 256], v2 = row[t + 512];
    __shared__ float red[4];
    float s = wave_red_sum(v0 + v1 + v2);
    if ((t & 63) == 0) red[t >> 6] = s;
    __syncthreads();
    float mean = (red[0] + red[1] + red[2] + red[3]) * (1.f / 768.f);
    __syncthreads();
    float d0 = v0 - mean, d1 = v1 - mean, d2 = v2 - mean;
    float q = wave_red_sum(d0 * d0 + d1 * d1 + d2 * d2);
    if ((t & 63) == 0) red[t >> 6] = q;
    __syncthreads();
    float inv = rsqrtf((red[0] + red[1] + red[2] + red[3]) * (1.f / 768.f) + 1e-7f);
    float* xr = x + (size_t)m * 768;
    xr[t] += d0 * inv * g[t] + bb[t];
    xr[t + 256] += d1 * inv * g[t + 256] + bb[t + 256];
    xr[t + 512] += d2 * inv * g[t + 512] + bb[t + 512];
}

__device__ __forceinline__ float fast_tanh(float z) {
    // tanh(z) = 1 - 2/(exp(2z)+1)
    return 1.f - 2.f / (__expf(2.f * z) + 1.f);
}

// u (4096,4096) bf16: glu = a * gelu_tanh(gate); LN over 2048; -> h2 bf16 (4096,2048)
__global__ __launch_bounds__(256) void glu_ln(const u16* __restrict__ u, u16* __restrict__ h2) {
    int m = blockIdx.x, t = threadIdx.x;
    const u16* row = u + (size_t)m * 4096;
    float gv[8];
    float s = 0.f;
#pragma unroll
    for (int jj = 0; jj < 8; jj++) {
        int j = jj * 256 + t;
        float a = bf2f(row[j]);
        float gt = bf2f(row[2048 + j]);
        float ge = 0.5f * gt * (1.f + fast_tanh(0.7978845608028654f * (gt + 0.044715f * gt * gt * gt)));
        gv[jj] = a * ge;
        s += gv[jj];
    }
    __shared__ float red[4];
    s = wave_red_sum(s);
    if ((t & 63) == 0) red[t >> 6] = s;
    __syncthreads();
    float mean = (red[0] + red[1] + red[2] + red[3]) * (1.f / 2048.f);
    __syncthreads();
    float q2 = 0.f;
#pragma unroll
    for (int jj = 0; jj < 8; jj++) {
        float d = gv[jj] - mean;
        q2 += d * d;
    }
    q2 = wave_red_sum(q2);
    if ((t & 63) == 0) red[t >> 6] = q2;
    __syncthreads();
    float inv = rsqrtf((red[0] + red[1] + red[2] + red[3]) * (1.f / 2048.f) + 1e-7f);
    u16* out = h2 + (size_t)m * 2048;
#pragma unroll
    for (int jj = 0; jj < 8; jj++) out[jj * 256 + t] = f2bf((gv[jj] - mean) * inv);
}

// ---------------- GEMM: C[m,n] = sum_k A[m,k]*B[n,k] (+bias), bf16 MFMA ----------------
// modes: 0 = fp32 out, 1 = bf16 out, 2 = qk scatter (out0=q,out1=k), 3 = v scatter, 4 = fp32 residual +=
__global__ __launch_bounds__(256) void gemm_nt(const u16* __restrict__ A, const u16* __restrict__ B,
                                               const float* __restrict__ bias, int M, int N, int K,
                                               int mode, void* __restrict__ out0, void* __restrict__ out1) {
    __shared__ __align__(16) u16 As[128 * 72];
    __shared__ __align__(16) u16 Bs[128 * 72];
    const int t = threadIdx.x;
    const int lane = t & 63, wave = t >> 6;
    const int wm = (wave >> 1) * 64, wn = (wave & 1) * 64;
    const int fr = lane & 15, qd = lane >> 4;
    const int m0 = blockIdx.y * 128, n0 = blockIdx.x * 128;
    const int row_s = t >> 3, g_s = t & 7;

    f32x4 zero4 = {0.f, 0.f, 0.f, 0.f};
    f32x4 acc[4][4];
#pragma unroll
    for (int i = 0; i < 4; i++)
#pragma unroll
        for (int j = 0; j < 4; j++) acc[i][j] = zero4;

    for (int k0 = 0; k0 < K; k0 += 64) {
        __syncthreads();
#pragma unroll
        for (int it = 0; it < 4; ++it) {
            int row = it * 32 + row_s;
            const float4* src = (const float4*)(A + (size_t)(m0 + row) * K + k0 + g_s * 8);
            *(float4*)&As[row * 72 + g_s * 8] = *src;
        }
#pragma unroll
        for (int it = 0; it < 4; ++it) {
            int row = it * 32 + row_s;
            const float4* src = (const float4*)(B + (size_t)(n0 + row) * K + k0 + g_s * 8);
            *(float4*)&Bs[row * 72 + g_s * 8] = *src;
        }
        __syncthreads();
#pragma unroll
        for (int s = 0; s < 2; ++s) {
            bf16x8 aF[4], bF[4];
#pragma unroll
            for (int i = 0; i < 4; i++) aF[i] = *(const bf16x8*)&As[(wm + i * 16 + fr) * 72 + s * 32 + qd * 8];
#pragma unroll
            for (int j = 0; j < 4; j++) bF[j] = *(const bf16x8*)&Bs[(wn + j * 16 + fr) * 72 + s * 32 + qd * 8];
#pragma unroll
            for (int i = 0; i < 4; i++)
#pragma unroll
                for (int j = 0; j < 4; j++)
                    acc[i][j] = __builtin_amdgcn_mfma_f32_16x16x32_bf16(aF[i], bF[j], acc[i][j], 0, 0, 0);
        }
    }

    // epilogue: D col = lane&15, row = (lane>>4)*4 + reg
#pragma unroll
    for (int j = 0; j < 4; j++) {
        int nn = n0 + wn + j * 16 + fr;
        float bval = bias ? bias[nn] : 0.f;
#pragma unroll
        for (int i = 0; i < 4; i++) {
#pragma unroll
            for (int rg = 0; rg < 4; ++rg) {
                int mm = m0 + wm + i * 16 + qd * 4 + rg;
                float val = acc[i][j][rg] + bval;
                if (mode == 0) {
                    ((float*)out0)[(size_t)mm * N + nn] = val;
                } else if (mode == 1) {
                    ((u16*)out0)[(size_t)mm * N + nn] = f2bf(val);
                } else if (mode == 2) {
                    int sidx = mm >> 3, bidx = mm & 7;
                    int nn2 = nn;
                    u16* dst = (u16*)out0;
                    if (nn2 >= 768) { dst = (u16*)out1; nn2 -= 768; }
                    int hh = nn2 >> 6, dd = nn2 & 63;
                    dst[(size_t)((bidx * 12 + hh) * 512 + sidx) * 64 + dd] = f2bf(val);
                } else if (mode == 3) {
                    int sidx = mm >> 3, bidx = mm & 7;
                    int hh = nn >> 6, dd = nn & 63;
                    ((u16*)out0)[(size_t)((bidx * 12 + hh) * 512 + sidx) * 64 + dd] = f2bf(val);
                } else {
                    ((float*)out0)[(size_t)mm * N + nn] += val;
                }
            }
        }
    }
}

// ---------------- position / attention ----------------

// pos[j,n] = rel[j,:] . Wqk[n,:] + bqk[n];  split into qpos/kpos bf16 (head, 64-row slots, d)
__global__ __launch_bounds__(256) void pos_kernel(const float* __restrict__ rel, const u16* __restrict__ wqk,
                                                  const float* __restrict__ bqk, u16* __restrict__ qposb,
                                                  u16* __restrict__ kposb) {
    int j = blockIdx.x, t = threadIdx.x;
    __shared__ float r[768];
    for (int i = t; i < 768; i += 256) r[i] = rel[(size_t)j * 768 + i];
    __syncthreads();
    for (int n = t; n < 1536; n += 256) {
        const u32* w32 = (const u32*)(wqk + (size_t)n * 768);
        float sum = bqk[n];
        for (int i = 0; i < 384; i++) {
            u32 u = w32[i];
            float lo = __builtin_bit_cast(float, u << 16);
            float hi = __builtin_bit_cast(float, u & 0xffff0000u);
            sum = fmaf(lo, r[2 * i], sum);
            sum = fmaf(hi, r[2 * i + 1], sum);
        }
        int hh = n >> 7, wd = n & 127;
        if (wd < 64) qposb[(size_t)(hh * 64 + j) * 64 + wd] = f2bf(sum);
        else kposb[(size_t)(hh * 64 + j) * 64 + (wd - 64)] = f2bf(sum);
    }
}

// c2p[bh,s,j] = q[bh,s,:].kpos[h,j,:];  p2c[bh,s,j] = k[bh,s,:].qpos[h,j,:]  via MFMA
// grid: (4 s-tiles of 128, 96 bh), block 256
__global__ __launch_bounds__(256) void posdot_kernel(const u16* __restrict__ qbuf, const u16* __restrict__ kbuf,
                                                     const u16* __restrict__ qposb, const u16* __restrict__ kposb,
                                                     float* __restrict__ c2p, float* __restrict__ p2c) {
    __shared__ __align__(16) u16 Qs[128 * 72];
    __shared__ __align__(16) u16 Ks[128 * 72];
    __shared__ __align__(16) u16 QP[64 * 72];
    __shared__ __align__(16) u16 KP[64 * 72];
    int t = threadIdx.x, lane = t & 63, w = t >> 6;
    int fr = lane & 15, qd = lane >> 4;
    int s0 = blockIdx.x * 128, bh = blockIdx.y, h = bh % 12;
    size_t base = (size_t)bh * 512 * 64;
    {
        int rs = t >> 1, cs = (t & 1) * 32;
#pragma unroll
        for (int c = 0; c < 4; c++) {
            *(float4*)&Qs[rs * 72 + cs + c * 8] = *(const float4*)(qbuf + base + (size_t)(s0 + rs) * 64 + cs + c * 8);
            *(float4*)&Ks[rs * 72 + cs + c * 8] = *(const float4*)(kbuf + base + (size_t)(s0 + rs) * 64 + cs + c * 8);
        }
        int rs2 = t >> 2, cs2 = (t & 3) * 16;
        const u16* qp = qposb + (size_t)h * 64 * 64;
        const u16* kp = kposb + (size_t)h * 64 * 64;
#pragma unroll
        for (int c = 0; c < 2; c++) {
            *(float4*)&QP[rs2 * 72 + cs2 + c * 8] = *(const float4*)(qp + (size_t)rs2 * 64 + cs2 + c * 8);
            *(float4*)&KP[rs2 * 72 + cs2 + c * 8] = *(const float4*)(kp + (size_t)rs2 * 64 + cs2 + c * 8);
        }
    }
    __syncthreads();
    f32x4 zero4 = {0.f, 0.f, 0.f, 0.f};
    f32x4 cacc[2][4], pacc[2][4];
#pragma unroll
    for (int i = 0; i < 2; i++)
#pragma unroll
        for (int j = 0; j < 4; j++) { cacc[i][j] = zero4; pacc[i][j] = zero4; }
#pragma unroll
    for (int s = 0; s < 2; s++) {
#pragma unroll
        for (int i = 0; i < 2; i++) {
            bf16x8 aQ = *(const bf16x8*)&Qs[(w * 32 + i * 16 + fr) * 72 + s * 32 + qd * 8];
            bf16x8 aK = *(const bf16x8*)&Ks[(w * 32 + i * 16 + fr) * 72 + s * 32 + qd * 8];
#pragma unroll
            for (int jf = 0; jf < 4; jf++) {
                bf16x8 bKP = *(const bf16x8*)&KP[(jf * 16 + fr) * 72 + s * 32 + qd * 8];
                bf16x8 bQP = *(const bf16x8*)&QP[(jf * 16 + fr) * 72 + s * 32 + qd * 8];
                cacc[i][jf] = __builtin_amdgcn_mfma_f32_16x16x32_bf16(aQ, bKP, cacc[i][jf], 0, 0, 0);
                pacc[i][jf] = __builtin_amdgcn_mfma_f32_16x16x32_bf16(aK, bQP, pacc[i][jf], 0, 0, 0);
            }
        }
    }
#pragma unroll
    for (int i = 0; i < 2; i++)
#pragma unroll
        for (int jf = 0; jf < 4; jf++)
#pragma unroll
            for (int rg = 0; rg < 4; rg++) {
                int row = w * 32 + i * 16 + qd * 4 + rg;
                int col = jf * 16 + fr;
                size_t o = (size_t)(bh * 512 + s0 + row) * 64 + col;
                c2p[o] = cacc[i][jf][rg];
                p2c[o] = pacc[i][jf][rg];
            }
}

// fused flash attention with disentangled bias, MFMA.
// grid: (8 q-tiles of 64, 96 bh), block 256 (4 waves, 16 q-rows each)
__global__ __launch_bounds__(256) void attn_mfma(const u16* __restrict__ qbuf, const u16* __restrict__ kbuf,
                                                 const u16* __restrict__ vbuf, const float* __restrict__ c2p,
                                                 const float* __restrict__ p2c, const int* __restrict__ posidx,
                                                 const unsigned char* __restrict__ mask, u16* __restrict__ ctxb) {
    __shared__ __align__(16) u16 Qs[64 * 72];
    __shared__ __align__(16) u16 Ks[64 * 72];
    __shared__ __align__(16) u16 Vt[64 * 72];  // [d][k]
    __shared__ __align__(16) u16 Ps[4][16 * 72];
    __shared__ float c2ps[64 * 64];
    const float scale = 0.07216878364870323f;  // 1/sqrt(192)
    int t = threadIdx.x, lane = t & 63, w = t >> 6;
    int fr = lane & 15, qd = lane >> 4;
    int qt = blockIdx.x, bh = blockIdx.y;
    int b = bh / 12, h = bh % 12;
    int q0 = qt * 64;
    size_t base = (size_t)bh * 512 * 64;

    // stage Q tile + c2p rows
    int rs = t >> 2, cs = (t & 3) * 16;
    {
        const u16* gq = qbuf + base + (size_t)(q0 + rs) * 64 + cs;
        *(float4*)&Qs[rs * 72 + cs] = *(const float4*)gq;
        *(float4*)&Qs[rs * 72 + cs + 8] = *(const float4*)(gq + 8);
        const float* gc = c2p + (size_t)(bh * 512 + q0 + rs) * 64 + cs;
#pragma unroll
        for (int c = 0; c < 4; c++) *(float4*)&c2ps[rs * 64 + cs + c * 4] = *(const float4*)(gc + c * 4);
    }

    f32x4 zero4 = {0.f, 0.f, 0.f, 0.f};
    f32x4 oacc[4];
#pragma unroll
    for (int j = 0; j < 4; j++) oacc[j] = zero4;
    float m_i[4] = {-1e30f, -1e30f, -1e30f, -1e30f};
    float l_i[4] = {0.f, 0.f, 0.f, 0.f};

    for (int kt = 0; kt < 8; kt++) {
        __syncthreads();
        {
            const u16* gk = kbuf + base + (size_t)(kt * 64 + rs) * 64 + cs;
            *(float4*)&Ks[rs * 72 + cs] = *(const float4*)gk;
            *(float4*)&Ks[rs * 72 + cs + 8] = *(const float4*)(gk + 8);
            const u16* gv = vbuf + base + (size_t)(kt * 64 + rs) * 64 + cs;
            u16 tmp[16];
            *(float4*)&tmp[0] = *(const float4*)gv;
            *(float4*)&tmp[8] = *(const float4*)(gv + 8);
#pragma unroll
            for (int j = 0; j < 16; j++) Vt[(cs + j) * 72 + rs] = tmp[j];
        }
        __syncthreads();

        // S = Q Kt^T
        f32x4 sacc[4];
#pragma unroll
        for (int j = 0; j < 4; j++) sacc[j] = zero4;
#pragma unroll
        for (int s = 0; s < 2; s++) {
            bf16x8 aQ = *(const bf16x8*)&Qs[(w * 16 + fr) * 72 + s * 32 + qd * 8];
#pragma unroll
            for (int jf = 0; jf < 4; jf++) {
                bf16x8 bK = *(const bf16x8*)&Ks[(jf * 16 + fr) * 72 + s * 32 + qd * 8];
                sacc[jf] = __builtin_amdgcn_mfma_f32_16x16x32_bf16(aQ, bK, sacc[jf], 0, 0, 0);
            }
        }

        // bias + mask
        float pvv[4][4];
#pragma unroll
        for (int jf = 0; jf < 4; jf++) {
            int kg = kt * 64 + jf * 16 + fr;
            bool mk = mask[b * 512 + kg] != 0;
            const float* p2crow = p2c + (size_t)(bh * 512 + kg) * 64;
            const int* pidx = posidx + kg;
#pragma unroll
            for (int rg = 0; rg < 4; rg++) {
                int ql = w * 16 + qd * 4 + rg;
                int qg = q0 + ql;
                int idx = pidx[qg * 512];
                float sval = (sacc[jf][rg] + c2ps[ql * 64 + idx] + p2crow[idx]) * scale;
                pvv[jf][rg] = mk ? -1e30f : sval;
            }
        }

        // online softmax per row (rows live across fr lanes)
#pragma unroll
        for (int rg = 0; rg < 4; rg++) {
            float rm = fmaxf(fmaxf(pvv[0][rg], pvv[1][rg]), fmaxf(pvv[2][rg], pvv[3][rg]));
#pragma unroll
            for (int msk = 1; msk < 16; msk <<= 1) rm = fmaxf(rm, __shfl_xor(rm, msk));
            float mnew = fmaxf(m_i[rg], rm);
            float alpha = __expf(m_i[rg] - mnew);
            m_i[rg] = mnew;
            float rsum = 0.f;
#pragma unroll
            for (int jf = 0; jf < 4; jf++) {
                float p = __expf(pvv[jf][rg] - mnew);
                pvv[jf][rg] = p;
                rsum += p;
            }
#pragma unroll
            for (int msk = 1; msk < 16; msk <<= 1) rsum += __shfl_xor(rsum, msk);
            l_i[rg] = l_i[rg] * alpha + rsum;
#pragma unroll
            for (int jf = 0; jf < 4; jf++) oacc[jf][rg] *= alpha;
        }

        // P -> LDS (A-operand relayout), per-wave private
#pragma unroll
        for (int jf = 0; jf < 4; jf++)
#pragma unroll
            for (int rg = 0; rg < 4; rg++) Ps[w][(qd * 4 + rg) * 72 + jf * 16 + fr] = f2bf(pvv[jf][rg]);

        // O += P V
#pragma unroll
        for (int s = 0; s < 2; s++) {
            bf16x8 aP = *(const bf16x8*)&Ps[w][fr * 72 + s * 32 + qd * 8];
#pragma unroll
            for (int jf = 0; jf < 4; jf++) {
                bf16x8 bV = *(const bf16x8*)&Vt[(jf * 16 + fr) * 72 + s * 32 + qd * 8];
                oacc[jf] = __builtin_amdgcn_mfma_f32_16x16x32_bf16(aP, bV, oacc[jf], 0, 0, 0);
            }
        }
    }

    // epilogue
#pragma unroll
    for (int jf = 0; jf < 4; jf++) {
#pragma unroll
        for (int rg = 0; rg < 4; rg++) {
            int qg = q0 + w * 16 + qd * 4 + rg;
            int d = jf * 16 + fr;
            float o = oacc[jf][rg] / l_i[rg];
            int m = qg * 8 + b;
            ctxb[(size_t)m * 768 + h * 64 + d] = f2bf(o);
        }
    }
}

// ---------------- host ----------------

extern "C" void kernel_launch(void* const* d_in, const int* in_sizes, int n_in, void* d_out, int out_size,
                              void* d_ws, size_t ws_size, hipStream_t stream) {
    const float* hidden = (const float*)d_in[0];
    const unsigned char* mask = (const unsigned char*)d_in[1];
    const float* relemb = (const float*)d_in[2];
    const float* Wqk = (const float*)d_in[3];
    const float* bqk = (const float*)d_in[4];
    const float* Wv = (const float*)d_in[5];
    const float* bv = (const float*)d_in[6];
    const float* Wo = (const float*)d_in[7];
    const float* bo = (const float*)d_in[8];
    const float* lng = (const float*)d_in[9];
    const float* lnb = (const float*)d_in[10];
    const float* W1 = (const float*)d_in[11];
    const float* W2 = (const float*)d_in[12];
    const int* posidx = (const int*)d_in[13];
    float* x = (float*)d_out;

    char* wsp = (char*)d_ws;
    auto alloc = [&](size_t bytes) -> char* {
        char* p = wsp;
        wsp += (bytes + 255) & ~(size_t)255;
        return p;
    };
    u16* wqk_bf = (u16*)alloc(6ull * 1536 * 768 * 2);
    u16* wv_bf = (u16*)alloc(6ull * 768 * 768 * 2);
    u16* wo_bf = (u16*)alloc(6ull * 768 * 768 * 2);
    u16* w1_bf = (u16*)alloc(6ull * 4096 * 768 * 2);
    u16* w2_bf = (u16*)alloc(6ull * 768 * 2048 * 2);
    u16* h_bf = (u16*)alloc(4096ull * 768 * 2);
    u16* qb = (u16*)alloc(96ull * 512 * 64 * 2);
    u16* kb = (u16*)alloc(96ull * 512 * 64 * 2);
    u16* vb = (u16*)alloc(96ull * 512 * 64 * 2);
    u16* qposb = (u16*)alloc(12ull * 64 * 64 * 2);
    u16* kposb = (u16*)alloc(12ull * 64 * 64 * 2);
    float* c2p = (float*)alloc(96ull * 512 * 64 * 4);
    float* p2c = (float*)alloc(96ull * 512 * 64 * 4);
    u16* ctxb = (u16*)alloc(4096ull * 768 * 2);
    float* ctxproj = (float*)alloc(4096ull * 768 * 4);
    u16* ubuf = (u16*)alloc(4096ull * 4096 * 2);
    u16* h2 = (u16*)alloc(4096ull * 2048 * 2);
    (void)ws_size;
    (void)in_sizes;
    (void)n_in;
    (void)out_size;

    auto conv = [&](const float* in, u16* out, size_t n) {
        size_t blocks = (n + 255) / 256;
        if (blocks > 8192) blocks = 8192;
        convert_kernel<<<dim3((unsigned)blocks), dim3(256), 0, stream>>>(in, out, (int)n);
    };
    conv(Wqk, wqk_bf, 6ull * 1536 * 768);
    conv(Wv, wv_bf, 6ull * 768 * 768);
    conv(Wo, wo_bf, 6ull * 768 * 768);
    conv(W1, w1_bf, 6ull * 4096 * 768);
    conv(W2, w2_bf, 6ull * 768 * 2048);
    copy_kernel<<<dim3(4096), dim3(256), 0, stream>>>(hidden, x, 4096 * 768);

    for (int l = 0; l < 6; l++) {
        ln_plain<<<dim3(4096), dim3(256), 0, stream>>>(x, h_bf);
        gemm_nt<<<dim3(12, 32), dim3(256), 0, stream>>>(h_bf, wqk_bf + (size_t)l * 1536 * 768, bqk + l * 1536,
                                                        4096, 1536, 768, 2, qb, kb);
        gemm_nt<<<dim3(6, 32), dim3(256), 0, stream>>>(h_bf, wv_bf + (size_t)l * 768 * 768, bv + l * 768,
                                                       4096, 768, 768, 3, vb, nullptr);
        pos_kernel<<<dim3(63), dim3(256), 0, stream>>>(relemb, wqk_bf + (size_t)l * 1536 * 768, bqk + l * 1536,
                                                       qposb, kposb);
        posdot_kernel<<<dim3(4, 96), dim3(256), 0, stream>>>(qb, kb, qposb, kposb, c2p, p2c);
        attn_mfma<<<dim3(8, 96), dim3(256), 0, stream>>>(qb, kb, vb, c2p, p2c, posidx, mask, ctxb);
        gemm_nt<<<dim3(6, 32), dim3(256), 0, stream>>>(ctxb, wo_bf + (size_t)l * 768 * 768, bo + l * 768,
                                                       4096, 768, 768, 0, ctxproj, nullptr);
        ln_res<<<dim3(4096), dim3(256), 0, stream>>>(ctxproj, lng + l * 768, lnb + l * 768, x);
        ln_plain<<<dim3(4096), dim3(256), 0, stream>>>(x, h_bf);
        gemm_nt<<<dim3(32, 32), dim3(256), 0, stream>>>(h_bf, w1_bf + (size_t)l * 4096 * 768, nullptr,
                                                        4096, 4096, 768, 1, ubuf, nullptr);
        glu_ln<<<dim3(4096), dim3(256), 0, stream>>>(ubuf, h2);
        gemm_nt<<<dim3(6, 32), dim3(256), 0, stream>>>(h2, w2_bf + (size_t)l * 768 * 2048, nullptr,
                                                       4096, 768, 2048, 4, x, nullptr);
    }
}

// Round 3
// 2309.177 us; speedup vs baseline: 2.7940x; 1.0878x over previous
//
#include <hip/hip_runtime.h>
#include <math.h>

typedef unsigned short u16;
typedef unsigned int u32;
typedef short bf16x8 __attribute__((ext_vector_type(8)));
typedef float f32x4 __attribute__((ext_vector_type(4)));

__device__ __forceinline__ float bf2f(u16 b) {
    u32 x = ((u32)b) << 16;
    return __builtin_bit_cast(float, x);
}
__device__ __forceinline__ u16 f2bf(float f) {
    u32 u = __builtin_bit_cast(u32, f);
    u32 r = (u + 0x7fffu + ((u >> 16) & 1u)) >> 16;  // RNE
    return (u16)r;
}
__device__ __forceinline__ float wave_red_sum(float v) {
#pragma unroll
    for (int o = 32; o; o >>= 1) v += __shfl_down(v, o, 64);
    return v;
}

// ---------------- elementwise helpers ----------------

__global__ void convert_kernel(const float* __restrict__ in, u16* __restrict__ out, int n) {
    for (int i = blockIdx.x * 256 + threadIdx.x; i < n; i += gridDim.x * 256)
        out[i] = f2bf(in[i]);
}

__global__ void copy_kernel(const float* __restrict__ in, float* __restrict__ out, int n) {
    for (int i = blockIdx.x * 256 + threadIdx.x; i < n; i += gridDim.x * 256)
        out[i] = in[i];
}

// relative-position bucket per diagonal d = q-k, d in [-511,511] -> diag8[d+511]
__global__ void diag_kernel(unsigned char* __restrict__ diag8) {
    int i = blockIdx.x * 256 + threadIdx.x;
    if (i >= 1023) return;
    int rel = i - 511;
    int sgn = (rel > 0) - (rel < 0);
    int arel = rel < 0 ? -rel : rel;
    double abs_pos = (rel < 16 && rel > -16) ? 15.0 : (double)arel;
    int bucket;
    if (abs_pos <= 16.0) {
        bucket = rel;
    } else {
        double lp = ceil(log(abs_pos / 16.0) / log(511.0 / 16.0) * 15.0);
        bucket = ((int)lp + 16) * sgn;
    }
    diag8[i] = (unsigned char)(31 + bucket);
}

// LN (no affine): x fp32 (4096,768) -> h bf16
__global__ __launch_bounds__(256) void ln_plain(const float* __restrict__ x, u16* __restrict__ h) {
    int m = blockIdx.x, t = threadIdx.x;
    const float* row = x + (size_t)m * 768;
    float v0 = row[t], v1 = row[t + 256], v2 = row[t + 512];
    __shared__ float red[4];
    float s = wave_red_sum(v0 + v1 + v2);
    if ((t & 63) == 0) red[t >> 6] = s;
    __syncthreads();
    float mean = (red[0] + red[1] + red[2] + red[3]) * (1.f / 768.f);
    __syncthreads();
    float d0 = v0 - mean, d1 = v1 - mean, d2 = v2 - mean;
    float q = wave_red_sum(d0 * d0 + d1 * d1 + d2 * d2);
    if ((t & 63) == 0) red[t >> 6] = q;
    __syncthreads();
    float inv = rsqrtf((red[0] + red[1] + red[2] + red[3]) * (1.f / 768.f) + 1e-7f);
    u16* hr = h + (size_t)m * 768;
    hr[t] = f2bf(d0 * inv);
    hr[t + 256] = f2bf(d1 * inv);
    hr[t + 512] = f2bf(d2 * inv);
}

// x += LN(c)*g + b
__global__ __launch_bounds__(256) void ln_res(const float* __restrict__ c, const float* __restrict__ g,
                                              const float* __restrict__ bb, float* __restrict__ x) {
    int m = blockIdx.x, t = threadIdx.x;
    const float* row = c + (size_t)m * 768;
    float v0 = row[t], v1 = row[t + 256], v2 = row[t + 512];
    __shared__ float red[4];
    float s = wave_red_sum(v0 + v1 + v2);
    if ((t & 63) == 0) red[t >> 6] = s;
    __syncthreads();
    float mean = (red[0] + red[1] + red[2] + red[3]) * (1.f / 768.f);
    __syncthreads();
    float d0 = v0 - mean, d1 = v1 - mean, d2 = v2 - mean;
    float q = wave_red_sum(d0 * d0 + d1 * d1 + d2 * d2);
    if ((t & 63) == 0) red[t >> 6] = q;
    __syncthreads();
    float inv = rsqrtf((red[0] + red[1] + red[2] + red[3]) * (1.f / 768.f) + 1e-7f);
    float* xr = x + (size_t)m * 768;
    xr[t] += d0 * inv * g[t] + bb[t];
    xr[t + 256] += d1 * inv * g[t + 256] + bb[t + 256];
    xr[t + 512] += d2 * inv * g[t + 512] + bb[t + 512];
}

__device__ __forceinline__ float fast_tanh(float z) {
    return 1.f - 2.f / (__expf(2.f * z) + 1.f);
}

// u (4096,4096) bf16: glu = a * gelu_tanh(gate); LN over 2048; -> h2 bf16 (4096,2048)
__global__ __launch_bounds__(256) void glu_ln(const u16* __restrict__ u, u16* __restrict__ h2) {
    int m = blockIdx.x, t = threadIdx.x;
    const u16* row = u + (size_t)m * 4096;
    float gv[8];
    float s = 0.f;
#pragma unroll
    for (int jj = 0; jj < 8; jj++) {
        int j = jj * 256 + t;
        float a = bf2f(row[j]);
        float gt = bf2f(row[2048 + j]);
        float ge = 0.5f * gt * (1.f + fast_tanh(0.7978845608028654f * (gt + 0.044715f * gt * gt * gt)));
        gv[jj] = a * ge;
        s += gv[jj];
    }
    __shared__ float red[4];
    s = wave_red_sum(s);
    if ((t & 63) == 0) red[t >> 6] = s;
    __syncthreads();
    float mean = (red[0] + red[1] + red[2] + red[3]) * (1.f / 2048.f);
    __syncthreads();
    float q2 = 0.f;
#pragma unroll
    for (int jj = 0; jj < 8; jj++) {
        float d = gv[jj] - mean;
        q2 += d * d;
    }
    q2 = wave_red_sum(q2);
    if ((t & 63) == 0) red[t >> 6] = q2;
    __syncthreads();
    float inv = rsqrtf((red[0] + red[1] + red[2] + red[3]) * (1.f / 2048.f) + 1e-7f);
    u16* out = h2 + (size_t)m * 2048;
#pragma unroll
    for (int jj = 0; jj < 8; jj++) out[jj * 256 + t] = f2bf((gv[jj] - mean) * inv);
}

// ---------------- GEMM: C[m,n] = sum_k A[m,k]*B[n,k] (+bias), bf16 MFMA ----------------
// modes: 0 = fp32 out, 1 = bf16 out, 2 = qk scatter (out0=q,out1=k), 3 = vT scatter [bh][d][s], 4 = fp32 residual +=
__global__ __launch_bounds__(256) void gemm_nt(const u16* __restrict__ A, const u16* __restrict__ B,
                                               const float* __restrict__ bias, int M, int N, int K,
                                               int mode, void* __restrict__ out0, void* __restrict__ out1) {
    __shared__ __align__(16) u16 As[128 * 72];
    __shared__ __align__(16) u16 Bs[128 * 72];
    const int t = threadIdx.x;
    const int lane = t & 63, wave = t >> 6;
    const int wm = (wave >> 1) * 64, wn = (wave & 1) * 64;
    const int fr = lane & 15, qd = lane >> 4;
    const int m0 = blockIdx.y * 128, n0 = blockIdx.x * 128;
    const int row_s = t >> 3, g_s = t & 7;

    f32x4 zero4 = {0.f, 0.f, 0.f, 0.f};
    f32x4 acc[4][4];
#pragma unroll
    for (int i = 0; i < 4; i++)
#pragma unroll
        for (int j = 0; j < 4; j++) acc[i][j] = zero4;

    for (int k0 = 0; k0 < K; k0 += 64) {
        __syncthreads();
#pragma unroll
        for (int it = 0; it < 4; ++it) {
            int row = it * 32 + row_s;
            const float4* src = (const float4*)(A + (size_t)(m0 + row) * K + k0 + g_s * 8);
            *(float4*)&As[row * 72 + g_s * 8] = *src;
        }
#pragma unroll
        for (int it = 0; it < 4; ++it) {
            int row = it * 32 + row_s;
            const float4* src = (const float4*)(B + (size_t)(n0 + row) * K + k0 + g_s * 8);
            *(float4*)&Bs[row * 72 + g_s * 8] = *src;
        }
        __syncthreads();
#pragma unroll
        for (int s = 0; s < 2; ++s) {
            bf16x8 aF[4], bF[4];
#pragma unroll
            for (int i = 0; i < 4; i++) aF[i] = *(const bf16x8*)&As[(wm + i * 16 + fr) * 72 + s * 32 + qd * 8];
#pragma unroll
            for (int j = 0; j < 4; j++) bF[j] = *(const bf16x8*)&Bs[(wn + j * 16 + fr) * 72 + s * 32 + qd * 8];
#pragma unroll
            for (int i = 0; i < 4; i++)
#pragma unroll
                for (int j = 0; j < 4; j++)
                    acc[i][j] = __builtin_amdgcn_mfma_f32_16x16x32_bf16(aF[i], bF[j], acc[i][j], 0, 0, 0);
        }
    }

    // epilogue: D col = lane&15, row = (lane>>4)*4 + reg
#pragma unroll
    for (int j = 0; j < 4; j++) {
        int nn = n0 + wn + j * 16 + fr;
        float bval = bias ? bias[nn] : 0.f;
#pragma unroll
        for (int i = 0; i < 4; i++) {
#pragma unroll
            for (int rg = 0; rg < 4; ++rg) {
                int mm = m0 + wm + i * 16 + qd * 4 + rg;
                float val = acc[i][j][rg] + bval;
                if (mode == 0) {
                    ((float*)out0)[(size_t)mm * N + nn] = val;
                } else if (mode == 1) {
                    ((u16*)out0)[(size_t)mm * N + nn] = f2bf(val);
                } else if (mode == 2) {
                    int sidx = mm >> 3, bidx = mm & 7;
                    int nn2 = nn;
                    u16* dst = (u16*)out0;
                    if (nn2 >= 768) { dst = (u16*)out1; nn2 -= 768; }
                    int hh = nn2 >> 6, dd = nn2 & 63;
                    dst[(size_t)((bidx * 12 + hh) * 512 + sidx) * 64 + dd] = f2bf(val);
                } else if (mode == 3) {
                    int sidx = mm >> 3, bidx = mm & 7;
                    int hh = nn >> 6, dd = nn & 63;
                    ((u16*)out0)[(size_t)((bidx * 12 + hh) * 64 + dd) * 512 + sidx] = f2bf(val);
                } else {
                    ((float*)out0)[(size_t)mm * N + nn] += val;
                }
            }
        }
    }
}

// ---------------- position / attention ----------------

// pos[j,n] = rel[j,:] . Wqk[n,:] + bqk[n];  split into qpos/kpos bf16 (head, 64-row slots, d)
__global__ __launch_bounds__(256) void pos_kernel(const float* __restrict__ rel, const u16* __restrict__ wqk,
                                                  const float* __restrict__ bqk, u16* __restrict__ qposb,
                                                  u16* __restrict__ kposb) {
    int j = blockIdx.x, t = threadIdx.x;
    __shared__ float r[768];
    for (int i = t; i < 768; i += 256) r[i] = rel[(size_t)j * 768 + i];
    __syncthreads();
    for (int n = t; n < 1536; n += 256) {
        const u32* w32 = (const u32*)(wqk + (size_t)n * 768);
        float sum = bqk[n];
        for (int i = 0; i < 384; i++) {
            u32 u = w32[i];
            float lo = __builtin_bit_cast(float, u << 16);
            float hi = __builtin_bit_cast(float, u & 0xffff0000u);
            sum = fmaf(lo, r[2 * i], sum);
            sum = fmaf(hi, r[2 * i + 1], sum);
        }
        int hh = n >> 7, wd = n & 127;
        if (wd < 64) qposb[(size_t)(hh * 64 + j) * 64 + wd] = f2bf(sum);
        else kposb[(size_t)(hh * 64 + j) * 64 + (wd - 64)] = f2bf(sum);
    }
}

// c2p[bh,s,j] = scale * q[bh,s,:].kpos[h,j,:];  p2c[bh,s,j] = scale * k[bh,s,:].qpos[h,j,:]  (bf16 out)
__global__ __launch_bounds__(256) void posdot_kernel(const u16* __restrict__ qbuf, const u16* __restrict__ kbuf,
                                                     const u16* __restrict__ qposb, const u16* __restrict__ kposb,
                                                     u16* __restrict__ c2pb, u16* __restrict__ p2cb) {
    __shared__ __align__(16) u16 Qs[128 * 72];
    __shared__ __align__(16) u16 Ks[128 * 72];
    __shared__ __align__(16) u16 QP[64 * 72];
    __shared__ __align__(16) u16 KP[64 * 72];
    const float scale = 0.07216878364870323f;  // 1/sqrt(192)
    int t = threadIdx.x, lane = t & 63, w = t >> 6;
    int fr = lane & 15, qd = lane >> 4;
    int s0 = blockIdx.x * 128, bh = blockIdx.y, h = bh % 12;
    size_t base = (size_t)bh * 512 * 64;
    {
        int rs = t >> 1, cs = (t & 1) * 32;
#pragma unroll
        for (int c = 0; c < 4; c++) {
            *(float4*)&Qs[rs * 72 + cs + c * 8] = *(const float4*)(qbuf + base + (size_t)(s0 + rs) * 64 + cs + c * 8);
            *(float4*)&Ks[rs * 72 + cs + c * 8] = *(const float4*)(kbuf + base + (size_t)(s0 + rs) * 64 + cs + c * 8);
        }
        int rs2 = t >> 2, cs2 = (t & 3) * 16;
        const u16* qp = qposb + (size_t)h * 64 * 64;
        const u16* kp = kposb + (size_t)h * 64 * 64;
#pragma unroll
        for (int c = 0; c < 2; c++) {
            *(float4*)&QP[rs2 * 72 + cs2 + c * 8] = *(const float4*)(qp + (size_t)rs2 * 64 + cs2 + c * 8);
            *(float4*)&KP[rs2 * 72 + cs2 + c * 8] = *(const float4*)(kp + (size_t)rs2 * 64 + cs2 + c * 8);
        }
    }
    __syncthreads();
    f32x4 zero4 = {0.f, 0.f, 0.f, 0.f};
    f32x4 cacc[2][4], pacc[2][4];
#pragma unroll
    for (int i = 0; i < 2; i++)
#pragma unroll
        for (int j = 0; j < 4; j++) { cacc[i][j] = zero4; pacc[i][j] = zero4; }
#pragma unroll
    for (int s = 0; s < 2; s++) {
#pragma unroll
        for (int i = 0; i < 2; i++) {
            bf16x8 aQ = *(const bf16x8*)&Qs[(w * 32 + i * 16 + fr) * 72 + s * 32 + qd * 8];
            bf16x8 aK = *(const bf16x8*)&Ks[(w * 32 + i * 16 + fr) * 72 + s * 32 + qd * 8];
#pragma unroll
            for (int jf = 0; jf < 4; jf++) {
                bf16x8 bKP = *(const bf16x8*)&KP[(jf * 16 + fr) * 72 + s * 32 + qd * 8];
                bf16x8 bQP = *(const bf16x8*)&QP[(jf * 16 + fr) * 72 + s * 32 + qd * 8];
                cacc[i][jf] = __builtin_amdgcn_mfma_f32_16x16x32_bf16(aQ, bKP, cacc[i][jf], 0, 0, 0);
                pacc[i][jf] = __builtin_amdgcn_mfma_f32_16x16x32_bf16(aK, bQP, pacc[i][jf], 0, 0, 0);
            }
        }
    }
#pragma unroll
    for (int i = 0; i < 2; i++)
#pragma unroll
        for (int jf = 0; jf < 4; jf++)
#pragma unroll
            for (int rg = 0; rg < 4; rg++) {
                int row = w * 32 + i * 16 + qd * 4 + rg;
                int col = jf * 16 + fr;
                size_t o = (size_t)(bh * 512 + s0 + row) * 64 + col;
                c2pb[o] = f2bf(cacc[i][jf][rg] * scale);
                p2cb[o] = f2bf(pacc[i][jf][rg] * scale);
            }
}

// fused flash attention with disentangled bias, MFMA.
// grid: (8 q-tiles of 64, 96 bh), block 256 (4 waves, 16 q-rows each)
// vbT layout: [bh][d][s] (pre-transposed). c2pb/p2cb bf16, pre-scaled.
__global__ __launch_bounds__(256) void attn_mfma(const u16* __restrict__ qbuf, const u16* __restrict__ kbuf,
                                                 const u16* __restrict__ vbT, const u16* __restrict__ c2pb,
                                                 const u16* __restrict__ p2cb, const unsigned char* __restrict__ diag8,
                                                 const unsigned char* __restrict__ mask, u16* __restrict__ ctxb) {
    __shared__ __align__(16) u16 Qs[64 * 72];
    __shared__ __align__(16) u16 KsPs[64 * 72];  // Ks during QK; per-wave Ps slices during PV
    __shared__ __align__(16) u16 Vt[64 * 72];    // [d][k]
    __shared__ __align__(16) u16 c2ps[64 * 72];  // [q][j]
    __shared__ __align__(16) u16 p2cs[64 * 72];  // [k][j]
    __shared__ unsigned char idxd[576];
    __shared__ unsigned char mks[512];
    const float scale = 0.07216878364870323f;  // 1/sqrt(192)
    int t = threadIdx.x, lane = t & 63, w = t >> 6;
    int fr = lane & 15, qd = lane >> 4;
    int qt = blockIdx.x, bh = blockIdx.y;
    int b = bh / 12, h = bh % 12;
    int q0 = qt * 64;
    size_t base = (size_t)bh * 512 * 64;
    int rs = t >> 2, cs = (t & 3) * 16;

    // stage Q tile, c2p rows, diag window, mask (once per block)
    {
        const u16* gq = qbuf + base + (size_t)(q0 + rs) * 64 + cs;
        *(float4*)&Qs[rs * 72 + cs] = *(const float4*)gq;
        *(float4*)&Qs[rs * 72 + cs + 8] = *(const float4*)(gq + 8);
        const u16* gc = c2pb + (size_t)(bh * 512 + q0 + rs) * 64 + cs;
        *(float4*)&c2ps[rs * 72 + cs] = *(const float4*)gc;
        *(float4*)&c2ps[rs * 72 + cs + 8] = *(const float4*)(gc + 8);
        for (int i = t; i < 575; i += 256) idxd[i] = diag8[q0 + i];
        for (int i = t; i < 512; i += 256) mks[i] = mask[b * 512 + i];
    }

    f32x4 zero4 = {0.f, 0.f, 0.f, 0.f};
    f32x4 oacc[4];
#pragma unroll
    for (int j = 0; j < 4; j++) oacc[j] = zero4;
    float m_i[4] = {-1e30f, -1e30f, -1e30f, -1e30f};
    float l_i[4] = {0.f, 0.f, 0.f, 0.f};
    const int ql0 = w * 16 + qd * 4;

    for (int kt = 0; kt < 8; kt++) {
        __syncthreads();
        {
            const u16* gk = kbuf + base + (size_t)(kt * 64 + rs) * 64 + cs;
            *(float4*)&KsPs[rs * 72 + cs] = *(const float4*)gk;
            *(float4*)&KsPs[rs * 72 + cs + 8] = *(const float4*)(gk + 8);
            const u16* gv = vbT + base + (size_t)rs * 512 + kt * 64 + cs;
            *(float4*)&Vt[rs * 72 + cs] = *(const float4*)gv;
            *(float4*)&Vt[rs * 72 + cs + 8] = *(const float4*)(gv + 8);
            const u16* gp = p2cb + (size_t)(bh * 512 + kt * 64 + rs) * 64 + cs;
            *(float4*)&p2cs[rs * 72 + cs] = *(const float4*)gp;
            *(float4*)&p2cs[rs * 72 + cs + 8] = *(const float4*)(gp + 8);
        }
        __syncthreads();

        // S = Q K^T
        f32x4 sacc[4];
#pragma unroll
        for (int j = 0; j < 4; j++) sacc[j] = zero4;
#pragma unroll
        for (int s = 0; s < 2; s++) {
            bf16x8 aQ = *(const bf16x8*)&Qs[(w * 16 + fr) * 72 + s * 32 + qd * 8];
#pragma unroll
            for (int jf = 0; jf < 4; jf++) {
                bf16x8 bK = *(const bf16x8*)&KsPs[(jf * 16 + fr) * 72 + s * 32 + qd * 8];
                sacc[jf] = __builtin_amdgcn_mfma_f32_16x16x32_bf16(aQ, bK, sacc[jf], 0, 0, 0);
            }
        }

        // bias + mask (all LDS)
        float pvv[4][4];
#pragma unroll
        for (int jf = 0; jf < 4; jf++) {
            int kl = jf * 16 + fr;
            int kg = kt * 64 + kl;
            bool mk = mks[kg] != 0;
#pragma unroll
            for (int rg = 0; rg < 4; rg++) {
                int ql = ql0 + rg;
                int j = idxd[ql - kg + 511];
                float bias = bf2f(c2ps[ql * 72 + j]) + bf2f(p2cs[kl * 72 + j]);
                float sval = sacc[jf][rg] * scale + bias;
                pvv[jf][rg] = mk ? -1e30f : sval;
            }
        }

        // online softmax per q-row (rows live across fr lanes)
#pragma unroll
        for (int rg = 0; rg < 4; rg++) {
            float rm = fmaxf(fmaxf(pvv[0][rg], pvv[1][rg]), fmaxf(pvv[2][rg], pvv[3][rg]));
#pragma unroll
            for (int msk = 1; msk < 16; msk <<= 1) rm = fmaxf(rm, __shfl_xor(rm, msk));
            float mnew = fmaxf(m_i[rg], rm);
            float alpha = __expf(m_i[rg] - mnew);
            m_i[rg] = mnew;
            float rsum = 0.f;
#pragma unroll
            for (int jf = 0; jf < 4; jf++) {
                float p = __expf(pvv[jf][rg] - mnew);
                pvv[jf][rg] = p;
                rsum += p;
            }
#pragma unroll
            for (int msk = 1; msk < 16; msk <<= 1) rsum += __shfl_xor(rsum, msk);
            l_i[rg] = l_i[rg] * alpha + rsum;
#pragma unroll
            for (int jf = 0; jf < 4; jf++) oacc[jf][rg] *= alpha;
        }

        __syncthreads();  // all waves done reading Ks before Ps overwrite

        // P -> LDS (A-operand relayout) into per-wave slice of KsPs
        u16* Psw = &KsPs[w * 16 * 72];
#pragma unroll
        for (int jf = 0; jf < 4; jf++)
#pragma unroll
            for (int rg = 0; rg < 4; rg++) Psw[(qd * 4 + rg) * 72 + jf * 16 + fr] = f2bf(pvv[jf][rg]);

        // O += P V
#pragma unroll
        for (int s = 0; s < 2; s++) {
            bf16x8 aP = *(const bf16x8*)&Psw[fr * 72 + s * 32 + qd * 8];
#pragma unroll
            for (int jf = 0; jf < 4; jf++) {
                bf16x8 bV = *(const bf16x8*)&Vt[(jf * 16 + fr) * 72 + s * 32 + qd * 8];
                oacc[jf] = __builtin_amdgcn_mfma_f32_16x16x32_bf16(aP, bV, oacc[jf], 0, 0, 0);
            }
        }
    }

    // epilogue
#pragma unroll
    for (int jf = 0; jf < 4; jf++) {
#pragma unroll
        for (int rg = 0; rg < 4; rg++) {
            int qg = q0 + ql0 + rg;
            int d = jf * 16 + fr;
            float o = oacc[jf][rg] / l_i[rg];
            int m = qg * 8 + b;
            ctxb[(size_t)m * 768 + h * 64 + d] = f2bf(o);
        }
    }
}

// ---------------- host ----------------

extern "C" void kernel_launch(void* const* d_in, const int* in_sizes, int n_in, void* d_out, int out_size,
                              void* d_ws, size_t ws_size, hipStream_t stream) {
    const float* hidden = (const float*)d_in[0];
    const unsigned char* mask = (const unsigned char*)d_in[1];
    const float* relemb = (const float*)d_in[2];
    const float* Wqk = (const float*)d_in[3];
    const float* bqk = (const float*)d_in[4];
    const float* Wv = (const float*)d_in[5];
    const float* bv = (const float*)d_in[6];
    const float* Wo = (const float*)d_in[7];
    const float* bo = (const float*)d_in[8];
    const float* lng = (const float*)d_in[9];
    const float* lnb = (const float*)d_in[10];
    const float* W1 = (const float*)d_in[11];
    const float* W2 = (const float*)d_in[12];
    float* x = (float*)d_out;

    char* wsp = (char*)d_ws;
    auto alloc = [&](size_t bytes) -> char* {
        char* p = wsp;
        wsp += (bytes + 255) & ~(size_t)255;
        return p;
    };
    u16* wqk_bf = (u16*)alloc(6ull * 1536 * 768 * 2);
    u16* wv_bf = (u16*)alloc(6ull * 768 * 768 * 2);
    u16* wo_bf = (u16*)alloc(6ull * 768 * 768 * 2);
    u16* w1_bf = (u16*)alloc(6ull * 4096 * 768 * 2);
    u16* w2_bf = (u16*)alloc(6ull * 768 * 2048 * 2);
    u16* h_bf = (u16*)alloc(4096ull * 768 * 2);
    u16* qb = (u16*)alloc(96ull * 512 * 64 * 2);
    u16* kb = (u16*)alloc(96ull * 512 * 64 * 2);
    u16* vbT = (u16*)alloc(96ull * 512 * 64 * 2);
    u16* qposb = (u16*)alloc(12ull * 64 * 64 * 2);
    u16* kposb = (u16*)alloc(12ull * 64 * 64 * 2);
    u16* c2pb = (u16*)alloc(96ull * 512 * 64 * 2);
    u16* p2cb = (u16*)alloc(96ull * 512 * 64 * 2);
    unsigned char* diag8 = (unsigned char*)alloc(1024);
    u16* ctxb = (u16*)alloc(4096ull * 768 * 2);
    float* ctxproj = (float*)alloc(4096ull * 768 * 4);
    u16* ubuf = (u16*)alloc(4096ull * 4096 * 2);
    u16* h2 = (u16*)alloc(4096ull * 2048 * 2);
    (void)ws_size;
    (void)in_sizes;
    (void)n_in;
    (void)out_size;

    auto conv = [&](const float* in, u16* out, size_t n) {
        size_t blocks = (n + 255) / 256;
        if (blocks > 8192) blocks = 8192;
        convert_kernel<<<dim3((unsigned)blocks), dim3(256), 0, stream>>>(in, out, (int)n);
    };
    conv(Wqk, wqk_bf, 6ull * 1536 * 768);
    conv(Wv, wv_bf, 6ull * 768 * 768);
    conv(Wo, wo_bf, 6ull * 768 * 768);
    conv(W1, w1_bf, 6ull * 4096 * 768);
    conv(W2, w2_bf, 6ull * 768 * 2048);
    copy_kernel<<<dim3(4096), dim3(256), 0, stream>>>(hidden, x, 4096 * 768);
    diag_kernel<<<dim3(4), dim3(256), 0, stream>>>(diag8);

    for (int l = 0; l < 6; l++) {
        ln_plain<<<dim3(4096), dim3(256), 0, stream>>>(x, h_bf);
        gemm_nt<<<dim3(12, 32), dim3(256), 0, stream>>>(h_bf, wqk_bf + (size_t)l * 1536 * 768, bqk + l * 1536,
                                                        4096, 1536, 768, 2, qb, kb);
        gemm_nt<<<dim3(6, 32), dim3(256), 0, stream>>>(h_bf, wv_bf + (size_t)l * 768 * 768, bv + l * 768,
                                                       4096, 768, 768, 3, vbT, nullptr);
        pos_kernel<<<dim3(63), dim3(256), 0, stream>>>(relemb, wqk_bf + (size_t)l * 1536 * 768, bqk + l * 1536,
                                                       qposb, kposb);
        posdot_kernel<<<dim3(4, 96), dim3(256), 0, stream>>>(qb, kb, qposb, kposb, c2pb, p2cb);
        attn_mfma<<<dim3(8, 96), dim3(256), 0, stream>>>(qb, kb, vbT, c2pb, p2cb, diag8, mask, ctxb);
        gemm_nt<<<dim3(6, 32), dim3(256), 0, stream>>>(ctxb, wo_bf + (size_t)l * 768 * 768, bo + l * 768,
                                                       4096, 768, 768, 0, ctxproj, nullptr);
        ln_res<<<dim3(4096), dim3(256), 0, stream>>>(ctxproj, lng + l * 768, lnb + l * 768, x);
        ln_plain<<<dim3(4096), dim3(256), 0, stream>>>(x, h_bf);
        gemm_nt<<<dim3(32, 32), dim3(256), 0, stream>>>(h_bf, w1_bf + (size_t)l * 4096 * 768, nullptr,
                                                        4096, 4096, 768, 1, ubuf, nullptr);
        glu_ln<<<dim3(4096), dim3(256), 0, stream>>>(ubuf, h2);
        gemm_nt<<<dim3(6, 32), dim3(256), 0, stream>>>(h2, w2_bf + (size_t)l * 768 * 2048, nullptr,
                                                       4096, 768, 2048, 4, x, nullptr);
    }
}

// Round 4
// 1861.080 us; speedup vs baseline: 3.4667x; 1.2408x over previous
//
#include <hip/hip_runtime.h>
#include <math.h>

typedef unsigned short u16;
typedef unsigned int u32;
typedef short bf16x8 __attribute__((ext_vector_type(8)));
typedef float f32x4 __attribute__((ext_vector_type(4)));

__device__ __forceinline__ float bf2f(u16 b) {
    u32 x = ((u32)b) << 16;
    return __builtin_bit_cast(float, x);
}
__device__ __forceinline__ u16 f2bf(float f) {
    u32 u = __builtin_bit_cast(u32, f);
    u32 r = (u + 0x7fffu + ((u >> 16) & 1u)) >> 16;  // RNE
    return (u16)r;
}
__device__ __forceinline__ float wave_red_sum(float v) {
#pragma unroll
    for (int o = 32; o; o >>= 1) v += __shfl_down(v, o, 64);
    return v;
}

// ---------------- elementwise helpers ----------------

__global__ void convert_kernel(const float* __restrict__ in, u16* __restrict__ out, int n) {
    for (int i = blockIdx.x * 256 + threadIdx.x; i < n; i += gridDim.x * 256)
        out[i] = f2bf(in[i]);
}

__global__ void copy_kernel(const float* __restrict__ in, float* __restrict__ out, int n) {
    for (int i = blockIdx.x * 256 + threadIdx.x; i < n; i += gridDim.x * 256)
        out[i] = in[i];
}

// relemb (63x768 fp32) -> relpad (64x768 bf16, row 63 = 0)
__global__ void relpad_kernel(const float* __restrict__ rel, u16* __restrict__ relpad) {
    int i = blockIdx.x * 256 + threadIdx.x;
    if (i >= 64 * 768) return;
    relpad[i] = (i < 63 * 768) ? f2bf(rel[i]) : (u16)0;
}

// relative-position bucket per diagonal d = q-k, d in [-511,511] -> diag8[d+511]
__global__ void diag_kernel(unsigned char* __restrict__ diag8) {
    int i = blockIdx.x * 256 + threadIdx.x;
    if (i >= 1023) return;
    int rel = i - 511;
    int sgn = (rel > 0) - (rel < 0);
    int arel = rel < 0 ? -rel : rel;
    double abs_pos = (rel < 16 && rel > -16) ? 15.0 : (double)arel;
    int bucket;
    if (abs_pos <= 16.0) {
        bucket = rel;
    } else {
        double lp = ceil(log(abs_pos / 16.0) / log(511.0 / 16.0) * 15.0);
        bucket = ((int)lp + 16) * sgn;
    }
    diag8[i] = (unsigned char)(31 + bucket);
}

// LN (no affine): x fp32 (4096,768) -> h bf16
__global__ __launch_bounds__(256) void ln_plain(const float* __restrict__ x, u16* __restrict__ h) {
    int m = blockIdx.x, t = threadIdx.x;
    const float* row = x + (size_t)m * 768;
    float v0 = row[t], v1 = row[t + 256], v2 = row[t + 512];
    __shared__ float red[4];
    float s = wave_red_sum(v0 + v1 + v2);
    if ((t & 63) == 0) red[t >> 6] = s;
    __syncthreads();
    float mean = (red[0] + red[1] + red[2] + red[3]) * (1.f / 768.f);
    __syncthreads();
    float d0 = v0 - mean, d1 = v1 - mean, d2 = v2 - mean;
    float q = wave_red_sum(d0 * d0 + d1 * d1 + d2 * d2);
    if ((t & 63) == 0) red[t >> 6] = q;
    __syncthreads();
    float inv = rsqrtf((red[0] + red[1] + red[2] + red[3]) * (1.f / 768.f) + 1e-7f);
    u16* hr = h + (size_t)m * 768;
    hr[t] = f2bf(d0 * inv);
    hr[t + 256] = f2bf(d1 * inv);
    hr[t + 512] = f2bf(d2 * inv);
}

// x += LN(c)*g + b
__global__ __launch_bounds__(256) void ln_res(const float* __restrict__ c, const float* __restrict__ g,
                                              const float* __restrict__ bb, float* __restrict__ x) {
    int m = blockIdx.x, t = threadIdx.x;
    const float* row = c + (size_t)m * 768;
    float v0 = row[t], v1 = row[t + 256], v2 = row[t + 512];
    __shared__ float red[4];
    float s = wave_red_sum(v0 + v1 + v2);
    if ((t & 63) == 0) red[t >> 6] = s;
    __syncthreads();
    float mean = (red[0] + red[1] + red[2] + red[3]) * (1.f / 768.f);
    __syncthreads();
    float d0 = v0 - mean, d1 = v1 - mean, d2 = v2 - mean;
    float q = wave_red_sum(d0 * d0 + d1 * d1 + d2 * d2);
    if ((t & 63) == 0) red[t >> 6] = q;
    __syncthreads();
    float inv = rsqrtf((red[0] + red[1] + red[2] + red[3]) * (1.f / 768.f) + 1e-7f);
    float* xr = x + (size_t)m * 768;
    xr[t] += d0 * inv * g[t] + bb[t];
    xr[t + 256] += d1 * inv * g[t + 256] + bb[t + 256];
    xr[t + 512] += d2 * inv * g[t + 512] + bb[t + 512];
}

__device__ __forceinline__ float fast_tanh(float z) {
    return 1.f - 2.f / (__expf(2.f * z) + 1.f);
}

// u (4096,4096) bf16: glu = a * gelu_tanh(gate); LN over 2048; -> h2 bf16 (4096,2048)
__global__ __launch_bounds__(256) void glu_ln(const u16* __restrict__ u, u16* __restrict__ h2) {
    int m = blockIdx.x, t = threadIdx.x;
    const u16* row = u + (size_t)m * 4096;
    float gv[8];
    float s = 0.f;
#pragma unroll
    for (int jj = 0; jj < 8; jj++) {
        int j = jj * 256 + t;
        float a = bf2f(row[j]);
        float gt = bf2f(row[2048 + j]);
        float ge = 0.5f * gt * (1.f + fast_tanh(0.7978845608028654f * (gt + 0.044715f * gt * gt * gt)));
        gv[jj] = a * ge;
        s += gv[jj];
    }
    __shared__ float red[4];
    s = wave_red_sum(s);
    if ((t & 63) == 0) red[t >> 6] = s;
    __syncthreads();
    float mean = (red[0] + red[1] + red[2] + red[3]) * (1.f / 2048.f);
    __syncthreads();
    float q2 = 0.f;
#pragma unroll
    for (int jj = 0; jj < 8; jj++) {
        float d = gv[jj] - mean;
        q2 += d * d;
    }
    q2 = wave_red_sum(q2);
    if ((t & 63) == 0) red[t >> 6] = q2;
    __syncthreads();
    float inv = rsqrtf((red[0] + red[1] + red[2] + red[3]) * (1.f / 2048.f) + 1e-7f);
    u16* out = h2 + (size_t)m * 2048;
#pragma unroll
    for (int jj = 0; jj < 8; jj++) out[jj * 256 + t] = f2bf((gv[jj] - mean) * inv);
}

// ---------------- GEMM: C[m,n] = sum_k A[m,k]*B[n,k] (+bias), bf16 MFMA ----------------
// modes: 0 = fp32 out, 1 = bf16 out, 2 = qk scatter (out0=q,out1=k), 3 = vT scatter [bh][d][s], 4 = fp32 residual +=
__global__ __launch_bounds__(256) void gemm_nt(const u16* __restrict__ A, const u16* __restrict__ B,
                                               const float* __restrict__ bias, int M, int N, int K,
                                               int mode, void* __restrict__ out0, void* __restrict__ out1) {
    __shared__ __align__(16) u16 As[128 * 72];
    __shared__ __align__(16) u16 Bs[128 * 72];
    const int t = threadIdx.x;
    const int lane = t & 63, wave = t >> 6;
    const int wm = (wave >> 1) * 64, wn = (wave & 1) * 64;
    const int fr = lane & 15, qd = lane >> 4;
    const int m0 = blockIdx.y * 128, n0 = blockIdx.x * 128;
    const int row_s = t >> 3, g_s = t & 7;

    f32x4 zero4 = {0.f, 0.f, 0.f, 0.f};
    f32x4 acc[4][4];
#pragma unroll
    for (int i = 0; i < 4; i++)
#pragma unroll
        for (int j = 0; j < 4; j++) acc[i][j] = zero4;

    for (int k0 = 0; k0 < K; k0 += 64) {
        __syncthreads();
#pragma unroll
        for (int it = 0; it < 4; ++it) {
            int row = it * 32 + row_s;
            const float4* src = (const float4*)(A + (size_t)(m0 + row) * K + k0 + g_s * 8);
            *(float4*)&As[row * 72 + g_s * 8] = *src;
        }
#pragma unroll
        for (int it = 0; it < 4; ++it) {
            int row = it * 32 + row_s;
            const float4* src = (const float4*)(B + (size_t)(n0 + row) * K + k0 + g_s * 8);
            *(float4*)&Bs[row * 72 + g_s * 8] = *src;
        }
        __syncthreads();
#pragma unroll
        for (int s = 0; s < 2; ++s) {
            bf16x8 aF[4], bF[4];
#pragma unroll
            for (int i = 0; i < 4; i++) aF[i] = *(const bf16x8*)&As[(wm + i * 16 + fr) * 72 + s * 32 + qd * 8];
#pragma unroll
            for (int j = 0; j < 4; j++) bF[j] = *(const bf16x8*)&Bs[(wn + j * 16 + fr) * 72 + s * 32 + qd * 8];
#pragma unroll
            for (int i = 0; i < 4; i++)
#pragma unroll
                for (int j = 0; j < 4; j++)
                    acc[i][j] = __builtin_amdgcn_mfma_f32_16x16x32_bf16(aF[i], bF[j], acc[i][j], 0, 0, 0);
        }
    }

    // epilogue: D col = lane&15, row = (lane>>4)*4 + reg
#pragma unroll
    for (int j = 0; j < 4; j++) {
        int nn = n0 + wn + j * 16 + fr;
        float bval = bias ? bias[nn] : 0.f;
#pragma unroll
        for (int i = 0; i < 4; i++) {
#pragma unroll
            for (int rg = 0; rg < 4; ++rg) {
                int mm = m0 + wm + i * 16 + qd * 4 + rg;
                float val = acc[i][j][rg] + bval;
                if (mode == 0) {
                    ((float*)out0)[(size_t)mm * N + nn] = val;
                } else if (mode == 1) {
                    ((u16*)out0)[(size_t)mm * N + nn] = f2bf(val);
                } else if (mode == 2) {
                    int sidx = mm >> 3, bidx = mm & 7;
                    int nn2 = nn;
                    u16* dst = (u16*)out0;
                    if (nn2 >= 768) { dst = (u16*)out1; nn2 -= 768; }
                    int hh = nn2 >> 6, dd = nn2 & 63;
                    dst[(size_t)((bidx * 12 + hh) * 512 + sidx) * 64 + dd] = f2bf(val);
                } else if (mode == 3) {
                    int sidx = mm >> 3, bidx = mm & 7;
                    int hh = nn >> 6, dd = nn & 63;
                    ((u16*)out0)[(size_t)((bidx * 12 + hh) * 64 + dd) * 512 + sidx] = f2bf(val);
                } else {
                    ((float*)out0)[(size_t)mm * N + nn] += val;
                }
            }
        }
    }
}

// ---------------- position / attention ----------------

// pos = relpad @ Wqk_l^T + bqk_l for all 6 layers; rows 0..62 -> qposb/kposb per layer.
// grid: (24 n-tiles of 64, 6 layers), block 256
__global__ __launch_bounds__(256) void pos_mfma(const u16* __restrict__ relpad, const u16* __restrict__ wqk_all,
                                                const float* __restrict__ bqk_all, u16* __restrict__ qposb,
                                                u16* __restrict__ kposb) {
    __shared__ __align__(16) u16 As[64 * 72];
    __shared__ __align__(16) u16 Bs[64 * 72];
    int t = threadIdx.x, lane = t & 63, w = t >> 6;
    int fr = lane & 15, qd = lane >> 4;
    int n0 = blockIdx.x * 64, l = blockIdx.y;
    const u16* B = wqk_all + (size_t)l * 1536 * 768;
    const float* bias = bqk_all + (size_t)l * 1536;
    int rs = t >> 2, cs = (t & 3) * 16;
    f32x4 zero4 = {0.f, 0.f, 0.f, 0.f};
    f32x4 acc[4];
#pragma unroll
    for (int j = 0; j < 4; j++) acc[j] = zero4;

    for (int k0 = 0; k0 < 768; k0 += 64) {
        __syncthreads();
        const u16* ga = relpad + (size_t)rs * 768 + k0 + cs;
        *(float4*)&As[rs * 72 + cs] = *(const float4*)ga;
        *(float4*)&As[rs * 72 + cs + 8] = *(const float4*)(ga + 8);
        const u16* gb = B + (size_t)(n0 + rs) * 768 + k0 + cs;
        *(float4*)&Bs[rs * 72 + cs] = *(const float4*)gb;
        *(float4*)&Bs[rs * 72 + cs + 8] = *(const float4*)(gb + 8);
        __syncthreads();
#pragma unroll
        for (int s = 0; s < 2; s++) {
            bf16x8 aF = *(const bf16x8*)&As[(w * 16 + fr) * 72 + s * 32 + qd * 8];
#pragma unroll
            for (int jf = 0; jf < 4; jf++) {
                bf16x8 bF = *(const bf16x8*)&Bs[(jf * 16 + fr) * 72 + s * 32 + qd * 8];
                acc[jf] = __builtin_amdgcn_mfma_f32_16x16x32_bf16(aF, bF, acc[jf], 0, 0, 0);
            }
        }
    }
#pragma unroll
    for (int jf = 0; jf < 4; jf++) {
        int nn = n0 + jf * 16 + fr;
        float bval = bias[nn];
        int hh = nn >> 7, wd = nn & 127;
#pragma unroll
        for (int rg = 0; rg < 4; rg++) {
            int m = w * 16 + qd * 4 + rg;
            if (m >= 63) continue;
            float val = acc[jf][rg] + bval;
            size_t o = ((size_t)l * 12 + hh) * 64 * 64 + (size_t)m * 64;
            if (wd < 64) qposb[o + wd] = f2bf(val);
            else kposb[o + (wd - 64)] = f2bf(val);
        }
    }
}

// c2p[bh,s,j] = scale * q[bh,s,:].kpos[h,j,:];  p2c[bh,s,j] = scale * k[bh,s,:].qpos[h,j,:]  (bf16 out)
__global__ __launch_bounds__(256) void posdot_kernel(const u16* __restrict__ qbuf, const u16* __restrict__ kbuf,
                                                     const u16* __restrict__ qposb, const u16* __restrict__ kposb,
                                                     u16* __restrict__ c2pb, u16* __restrict__ p2cb) {
    __shared__ __align__(16) u16 Qs[128 * 72];
    __shared__ __align__(16) u16 Ks[128 * 72];
    __shared__ __align__(16) u16 QP[64 * 72];
    __shared__ __align__(16) u16 KP[64 * 72];
    const float scale = 0.07216878364870323f;  // 1/sqrt(192)
    int t = threadIdx.x, lane = t & 63, w = t >> 6;
    int fr = lane & 15, qd = lane >> 4;
    int s0 = blockIdx.x * 128, bh = blockIdx.y, h = bh % 12;
    size_t base = (size_t)bh * 512 * 64;
    {
        int rs = t >> 1, cs = (t & 1) * 32;
#pragma unroll
        for (int c = 0; c < 4; c++) {
            *(float4*)&Qs[rs * 72 + cs + c * 8] = *(const float4*)(qbuf + base + (size_t)(s0 + rs) * 64 + cs + c * 8);
            *(float4*)&Ks[rs * 72 + cs + c * 8] = *(const float4*)(kbuf + base + (size_t)(s0 + rs) * 64 + cs + c * 8);
        }
        int rs2 = t >> 2, cs2 = (t & 3) * 16;
        const u16* qp = qposb + (size_t)h * 64 * 64;
        const u16* kp = kposb + (size_t)h * 64 * 64;
#pragma unroll
        for (int c = 0; c < 2; c++) {
            *(float4*)&QP[rs2 * 72 + cs2 + c * 8] = *(const float4*)(qp + (size_t)rs2 * 64 + cs2 + c * 8);
            *(float4*)&KP[rs2 * 72 + cs2 + c * 8] = *(const float4*)(kp + (size_t)rs2 * 64 + cs2 + c * 8);
        }
    }
    __syncthreads();
    f32x4 zero4 = {0.f, 0.f, 0.f, 0.f};
    f32x4 cacc[2][4], pacc[2][4];
#pragma unroll
    for (int i = 0; i < 2; i++)
#pragma unroll
        for (int j = 0; j < 4; j++) { cacc[i][j] = zero4; pacc[i][j] = zero4; }
#pragma unroll
    for (int s = 0; s < 2; s++) {
#pragma unroll
        for (int i = 0; i < 2; i++) {
            bf16x8 aQ = *(const bf16x8*)&Qs[(w * 32 + i * 16 + fr) * 72 + s * 32 + qd * 8];
            bf16x8 aK = *(const bf16x8*)&Ks[(w * 32 + i * 16 + fr) * 72 + s * 32 + qd * 8];
#pragma unroll
            for (int jf = 0; jf < 4; jf++) {
                bf16x8 bKP = *(const bf16x8*)&KP[(jf * 16 + fr) * 72 + s * 32 + qd * 8];
                bf16x8 bQP = *(const bf16x8*)&QP[(jf * 16 + fr) * 72 + s * 32 + qd * 8];
                cacc[i][jf] = __builtin_amdgcn_mfma_f32_16x16x32_bf16(aQ, bKP, cacc[i][jf], 0, 0, 0);
                pacc[i][jf] = __builtin_amdgcn_mfma_f32_16x16x32_bf16(aK, bQP, pacc[i][jf], 0, 0, 0);
            }
        }
    }
#pragma unroll
    for (int i = 0; i < 2; i++)
#pragma unroll
        for (int jf = 0; jf < 4; jf++)
#pragma unroll
            for (int rg = 0; rg < 4; rg++) {
                int row = w * 32 + i * 16 + qd * 4 + rg;
                int col = jf * 16 + fr;
                size_t o = (size_t)(bh * 512 + s0 + row) * 64 + col;
                c2pb[o] = f2bf(cacc[i][jf][rg] * scale);
                p2cb[o] = f2bf(pacc[i][jf][rg] * scale);
            }
}

// fused flash attention with disentangled bias, MFMA.
// grid: (8 q-tiles of 64, 96 bh), block 256 (4 waves, 16 q-rows each)
// vbT layout: [bh][d][s] (pre-transposed). c2pb/p2cb bf16, pre-scaled.
__global__ __launch_bounds__(256) void attn_mfma(const u16* __restrict__ qbuf, const u16* __restrict__ kbuf,
                                                 const u16* __restrict__ vbT, const u16* __restrict__ c2pb,
                                                 const u16* __restrict__ p2cb, const unsigned char* __restrict__ diag8,
                                                 const unsigned char* __restrict__ mask, u16* __restrict__ ctxb) {
    __shared__ __align__(16) u16 Qs[64 * 72];
    __shared__ __align__(16) u16 KsPs[64 * 72];  // Ks during QK; per-wave Ps slices during PV
    __shared__ __align__(16) u16 Vt[64 * 72];    // [d][k]
    __shared__ __align__(16) u16 c2ps[64 * 72];  // [q][j]
    __shared__ __align__(16) u16 p2cs[64 * 72];  // [k][j]
    __shared__ unsigned char idxd[576];
    __shared__ unsigned char mks[512];
    const float scale = 0.07216878364870323f;  // 1/sqrt(192)
    int t = threadIdx.x, lane = t & 63, w = t >> 6;
    int fr = lane & 15, qd = lane >> 4;
    int qt = blockIdx.x, bh = blockIdx.y;
    int b = bh / 12, h = bh % 12;
    int q0 = qt * 64;
    size_t base = (size_t)bh * 512 * 64;
    int rs = t >> 2, cs = (t & 3) * 16;

    // stage Q tile, c2p rows, diag window, mask (once per block)
    {
        const u16* gq = qbuf + base + (size_t)(q0 + rs) * 64 + cs;
        *(float4*)&Qs[rs * 72 + cs] = *(const float4*)gq;
        *(float4*)&Qs[rs * 72 + cs + 8] = *(const float4*)(gq + 8);
        const u16* gc = c2pb + (size_t)(bh * 512 + q0 + rs) * 64 + cs;
        *(float4*)&c2ps[rs * 72 + cs] = *(const float4*)gc;
        *(float4*)&c2ps[rs * 72 + cs + 8] = *(const float4*)(gc + 8);
        for (int i = t; i < 575; i += 256) idxd[i] = diag8[q0 + i];
        for (int i = t; i < 512; i += 256) mks[i] = mask[b * 512 + i];
    }

    f32x4 zero4 = {0.f, 0.f, 0.f, 0.f};
    f32x4 oacc[4];
#pragma unroll
    for (int j = 0; j < 4; j++) oacc[j] = zero4;
    float m_i[4] = {-1e30f, -1e30f, -1e30f, -1e30f};
    float l_i[4] = {0.f, 0.f, 0.f, 0.f};
    const int ql0 = w * 16 + qd * 4;

    for (int kt = 0; kt < 8; kt++) {
        __syncthreads();
        {
            const u16* gk = kbuf + base + (size_t)(kt * 64 + rs) * 64 + cs;
            *(float4*)&KsPs[rs * 72 + cs] = *(const float4*)gk;
            *(float4*)&KsPs[rs * 72 + cs + 8] = *(const float4*)(gk + 8);
            const u16* gv = vbT + base + (size_t)rs * 512 + kt * 64 + cs;
            *(float4*)&Vt[rs * 72 + cs] = *(const float4*)gv;
            *(float4*)&Vt[rs * 72 + cs + 8] = *(const float4*)(gv + 8);
            const u16* gp = p2cb + (size_t)(bh * 512 + kt * 64 + rs) * 64 + cs;
            *(float4*)&p2cs[rs * 72 + cs] = *(const float4*)gp;
            *(float4*)&p2cs[rs * 72 + cs + 8] = *(const float4*)(gp + 8);
        }
        __syncthreads();

        // S = Q K^T
        f32x4 sacc[4];
#pragma unroll
        for (int j = 0; j < 4; j++) sacc[j] = zero4;
#pragma unroll
        for (int s = 0; s < 2; s++) {
            bf16x8 aQ = *(const bf16x8*)&Qs[(w * 16 + fr) * 72 + s * 32 + qd * 8];
#pragma unroll
            for (int jf = 0; jf < 4; jf++) {
                bf16x8 bK = *(const bf16x8*)&KsPs[(jf * 16 + fr) * 72 + s * 32 + qd * 8];
                sacc[jf] = __builtin_amdgcn_mfma_f32_16x16x32_bf16(aQ, bK, sacc[jf], 0, 0, 0);
            }
        }

        // bias + mask (all LDS)
        float pvv[4][4];
#pragma unroll
        for (int jf = 0; jf < 4; jf++) {
            int kl = jf * 16 + fr;
            int kg = kt * 64 + kl;
            bool mk = mks[kg] != 0;
#pragma unroll
            for (int rg = 0; rg < 4; rg++) {
                int ql = ql0 + rg;
                int j = idxd[ql - kg + 511];
                float bias = bf2f(c2ps[ql * 72 + j]) + bf2f(p2cs[kl * 72 + j]);
                float sval = sacc[jf][rg] * scale + bias;
                pvv[jf][rg] = mk ? -1e30f : sval;
            }
        }

        // online softmax per q-row (rows live across fr lanes)
#pragma unroll
        for (int rg = 0; rg < 4; rg++) {
            float rm = fmaxf(fmaxf(pvv[0][rg], pvv[1][rg]), fmaxf(pvv[2][rg], pvv[3][rg]));
#pragma unroll
            for (int msk = 1; msk < 16; msk <<= 1) rm = fmaxf(rm, __shfl_xor(rm, msk));
            float mnew = fmaxf(m_i[rg], rm);
            float alpha = __expf(m_i[rg] - mnew);
            m_i[rg] = mnew;
            float rsum = 0.f;
#pragma unroll
            for (int jf = 0; jf < 4; jf++) {
                float p = __expf(pvv[jf][rg] - mnew);
                pvv[jf][rg] = p;
                rsum += p;
            }
#pragma unroll
            for (int msk = 1; msk < 16; msk <<= 1) rsum += __shfl_xor(rsum, msk);
            l_i[rg] = l_i[rg] * alpha + rsum;
#pragma unroll
            for (int jf = 0; jf < 4; jf++) oacc[jf][rg] *= alpha;
        }

        __syncthreads();  // all waves done reading Ks before Ps overwrite

        // P -> LDS (A-operand relayout) into per-wave slice of KsPs
        u16* Psw = &KsPs[w * 16 * 72];
#pragma unroll
        for (int jf = 0; jf < 4; jf++)
#pragma unroll
            for (int rg = 0; rg < 4; rg++) Psw[(qd * 4 + rg) * 72 + jf * 16 + fr] = f2bf(pvv[jf][rg]);

        // O += P V
#pragma unroll
        for (int s = 0; s < 2; s++) {
            bf16x8 aP = *(const bf16x8*)&Psw[fr * 72 + s * 32 + qd * 8];
#pragma unroll
            for (int jf = 0; jf < 4; jf++) {
                bf16x8 bV = *(const bf16x8*)&Vt[(jf * 16 + fr) * 72 + s * 32 + qd * 8];
                oacc[jf] = __builtin_amdgcn_mfma_f32_16x16x32_bf16(aP, bV, oacc[jf], 0, 0, 0);
            }
        }
    }

    // epilogue
#pragma unroll
    for (int jf = 0; jf < 4; jf++) {
#pragma unroll
        for (int rg = 0; rg < 4; rg++) {
            int qg = q0 + ql0 + rg;
            int d = jf * 16 + fr;
            float o = oacc[jf][rg] / l_i[rg];
            int m = qg * 8 + b;
            ctxb[(size_t)m * 768 + h * 64 + d] = f2bf(o);
        }
    }
}

// ---------------- host ----------------

extern "C" void kernel_launch(void* const* d_in, const int* in_sizes, int n_in, void* d_out, int out_size,
                              void* d_ws, size_t ws_size, hipStream_t stream) {
    const float* hidden = (const float*)d_in[0];
    const unsigned char* mask = (const unsigned char*)d_in[1];
    const float* relemb = (const float*)d_in[2];
    const float* Wqk = (const float*)d_in[3];
    const float* bqk = (const float*)d_in[4];
    const float* Wv = (const float*)d_in[5];
    const float* bv = (const float*)d_in[6];
    const float* Wo = (const float*)d_in[7];
    const float* bo = (const float*)d_in[8];
    const float* lng = (const float*)d_in[9];
    const float* lnb = (const float*)d_in[10];
    const float* W1 = (const float*)d_in[11];
    const float* W2 = (const float*)d_in[12];
    float* x = (float*)d_out;

    char* wsp = (char*)d_ws;
    auto alloc = [&](size_t bytes) -> char* {
        char* p = wsp;
        wsp += (bytes + 255) & ~(size_t)255;
        return p;
    };
    u16* wqk_bf = (u16*)alloc(6ull * 1536 * 768 * 2);
    u16* wv_bf = (u16*)alloc(6ull * 768 * 768 * 2);
    u16* wo_bf = (u16*)alloc(6ull * 768 * 768 * 2);
    u16* w1_bf = (u16*)alloc(6ull * 4096 * 768 * 2);
    u16* w2_bf = (u16*)alloc(6ull * 768 * 2048 * 2);
    u16* h_bf = (u16*)alloc(4096ull * 768 * 2);
    u16* qb = (u16*)alloc(96ull * 512 * 64 * 2);
    u16* kb = (u16*)alloc(96ull * 512 * 64 * 2);
    u16* vbT = (u16*)alloc(96ull * 512 * 64 * 2);
    u16* qposb = (u16*)alloc(6ull * 12 * 64 * 64 * 2);
    u16* kposb = (u16*)alloc(6ull * 12 * 64 * 64 * 2);
    u16* relpad = (u16*)alloc(64ull * 768 * 2);
    u16* c2pb = (u16*)alloc(96ull * 512 * 64 * 2);
    u16* p2cb = (u16*)alloc(96ull * 512 * 64 * 2);
    unsigned char* diag8 = (unsigned char*)alloc(1024);
    u16* ctxb = (u16*)alloc(4096ull * 768 * 2);
    float* ctxproj = (float*)alloc(4096ull * 768 * 4);
    u16* ubuf = (u16*)alloc(4096ull * 4096 * 2);
    u16* h2 = (u16*)alloc(4096ull * 2048 * 2);
    (void)ws_size;
    (void)in_sizes;
    (void)n_in;
    (void)out_size;

    auto conv = [&](const float* in, u16* out, size_t n) {
        size_t blocks = (n + 255) / 256;
        if (blocks > 8192) blocks = 8192;
        convert_kernel<<<dim3((unsigned)blocks), dim3(256), 0, stream>>>(in, out, (int)n);
    };
    conv(Wqk, wqk_bf, 6ull * 1536 * 768);
    conv(Wv, wv_bf, 6ull * 768 * 768);
    conv(Wo, wo_bf, 6ull * 768 * 768);
    conv(W1, w1_bf, 6ull * 4096 * 768);
    conv(W2, w2_bf, 6ull * 768 * 2048);
    copy_kernel<<<dim3(4096), dim3(256), 0, stream>>>(hidden, x, 4096 * 768);
    diag_kernel<<<dim3(4), dim3(256), 0, stream>>>(diag8);
    relpad_kernel<<<dim3(192), dim3(256), 0, stream>>>(relemb, relpad);
    pos_mfma<<<dim3(24, 6), dim3(256), 0, stream>>>(relpad, wqk_bf, bqk, qposb, kposb);

    for (int l = 0; l < 6; l++) {
        ln_plain<<<dim3(4096), dim3(256), 0, stream>>>(x, h_bf);
        gemm_nt<<<dim3(12, 32), dim3(256), 0, stream>>>(h_bf, wqk_bf + (size_t)l * 1536 * 768, bqk + l * 1536,
                                                        4096, 1536, 768, 2, qb, kb);
        gemm_nt<<<dim3(6, 32), dim3(256), 0, stream>>>(h_bf, wv_bf + (size_t)l * 768 * 768, bv + l * 768,
                                                       4096, 768, 768, 3, vbT, nullptr);
        posdot_kernel<<<dim3(4, 96), dim3(256), 0, stream>>>(qb, kb, qposb + (size_t)l * 12 * 64 * 64,
                                                             kposb + (size_t)l * 12 * 64 * 64, c2pb, p2cb);
        attn_mfma<<<dim3(8, 96), dim3(256), 0, stream>>>(qb, kb, vbT, c2pb, p2cb, diag8, mask, ctxb);
        gemm_nt<<<dim3(6, 32), dim3(256), 0, stream>>>(ctxb, wo_bf + (size_t)l * 768 * 768, bo + l * 768,
                                                       4096, 768, 768, 0, ctxproj, nullptr);
        ln_res<<<dim3(4096), dim3(256), 0, stream>>>(ctxproj, lng + l * 768, lnb + l * 768, x);
        ln_plain<<<dim3(4096), dim3(256), 0, stream>>>(x, h_bf);
        gemm_nt<<<dim3(32, 32), dim3(256), 0, stream>>>(h_bf, w1_bf + (size_t)l * 4096 * 768, nullptr,
                                                        4096, 4096, 768, 1, ubuf, nullptr);
        glu_ln<<<dim3(4096), dim3(256), 0, stream>>>(ubuf, h2);
        gemm_nt<<<dim3(6, 32), dim3(256), 0, stream>>>(h2, w2_bf + (size_t)l * 768 * 2048, nullptr,
                                                       4096, 768, 2048, 4, x, nullptr);
    }
}

// Round 5
// 1657.709 us; speedup vs baseline: 3.8920x; 1.1227x over previous
//
#include <hip/hip_runtime.h>
#include <math.h>

typedef unsigned short u16;
typedef unsigned int u32;
typedef short bf16x8 __attribute__((ext_vector_type(8)));
typedef float f32x4 __attribute__((ext_vector_type(4)));

__device__ __forceinline__ float bf2f(u16 b) {
    u32 x = ((u32)b) << 16;
    return __builtin_bit_cast(float, x);
}
__device__ __forceinline__ u16 f2bf(float f) {
    u32 u = __builtin_bit_cast(u32, f);
    u32 r = (u + 0x7fffu + ((u >> 16) & 1u)) >> 16;  // RNE
    return (u16)r;
}
__device__ __forceinline__ float wave_red_sum(float v) {
#pragma unroll
    for (int o = 32; o; o >>= 1) v += __shfl_down(v, o, 64);
    return v;
}

// ---------------- elementwise helpers ----------------

__global__ void convert_kernel(const float* __restrict__ in, u16* __restrict__ out, int n) {
    for (int i = blockIdx.x * 256 + threadIdx.x; i < n; i += gridDim.x * 256)
        out[i] = f2bf(in[i]);
}

// build combined qkv weight: rows 0..1535 from Wqk, rows 1536..2303 from Wv (per layer)
__global__ void convert_qkv_kernel(const float* __restrict__ Wqk, const float* __restrict__ Wv,
                                   u16* __restrict__ out) {
    const int per = 2304 * 768;
    for (int i = blockIdx.x * 256 + threadIdx.x; i < 6 * per; i += gridDim.x * 256) {
        int l = i / per, r = i % per;
        int row = r / 768, col = r % 768;
        float v = (row < 1536) ? Wqk[((size_t)l * 1536 + row) * 768 + col]
                               : Wv[((size_t)l * 768 + (row - 1536)) * 768 + col];
        out[i] = f2bf(v);
    }
}

__global__ void bias_qkv_kernel(const float* __restrict__ bqk, const float* __restrict__ bv,
                                float* __restrict__ out) {
    for (int i = blockIdx.x * 256 + threadIdx.x; i < 6 * 2304; i += gridDim.x * 256) {
        int l = i / 2304, r = i % 2304;
        out[i] = (r < 1536) ? bqk[l * 1536 + r] : bv[l * 768 + (r - 1536)];
    }
}

__global__ void copy_kernel(const float* __restrict__ in, float* __restrict__ out, int n) {
    for (int i = blockIdx.x * 256 + threadIdx.x; i < n; i += gridDim.x * 256)
        out[i] = in[i];
}

// relemb (63x768 fp32) -> relpad (64x768 bf16, row 63 = 0)
__global__ void relpad_kernel(const float* __restrict__ rel, u16* __restrict__ relpad) {
    int i = blockIdx.x * 256 + threadIdx.x;
    if (i >= 64 * 768) return;
    relpad[i] = (i < 63 * 768) ? f2bf(rel[i]) : (u16)0;
}

// relative-position bucket per diagonal d = q-k, d in [-511,511] -> diag8[d+511]
__global__ void diag_kernel(unsigned char* __restrict__ diag8) {
    int i = blockIdx.x * 256 + threadIdx.x;
    if (i >= 1023) return;
    int rel = i - 511;
    int sgn = (rel > 0) - (rel < 0);
    int arel = rel < 0 ? -rel : rel;
    double abs_pos = (rel < 16 && rel > -16) ? 15.0 : (double)arel;
    int bucket;
    if (abs_pos <= 16.0) {
        bucket = rel;
    } else {
        double lp = ceil(log(abs_pos / 16.0) / log(511.0 / 16.0) * 15.0);
        bucket = ((int)lp + 16) * sgn;
    }
    diag8[i] = (unsigned char)(31 + bucket);
}

// LN (no affine): x fp32 (4096,768) -> h bf16
__global__ __launch_bounds__(256) void ln_plain(const float* __restrict__ x, u16* __restrict__ h) {
    int m = blockIdx.x, t = threadIdx.x;
    const float* row = x + (size_t)m * 768;
    float v0 = row[t], v1 = row[t + 256], v2 = row[t + 512];
    __shared__ float red[4];
    float s = wave_red_sum(v0 + v1 + v2);
    if ((t & 63) == 0) red[t >> 6] = s;
    __syncthreads();
    float mean = (red[0] + red[1] + red[2] + red[3]) * (1.f / 768.f);
    __syncthreads();
    float d0 = v0 - mean, d1 = v1 - mean, d2 = v2 - mean;
    float q = wave_red_sum(d0 * d0 + d1 * d1 + d2 * d2);
    if ((t & 63) == 0) red[t >> 6] = q;
    __syncthreads();
    float inv = rsqrtf((red[0] + red[1] + red[2] + red[3]) * (1.f / 768.f) + 1e-7f);
    u16* hr = h + (size_t)m * 768;
    hr[t] = f2bf(d0 * inv);
    hr[t + 256] = f2bf(d1 * inv);
    hr[t + 512] = f2bf(d2 * inv);
}

// x += LN(c)*g + b
__global__ __launch_bounds__(256) void ln_res(const float* __restrict__ c, const float* __restrict__ g,
                                              const float* __restrict__ bb, float* __restrict__ x) {
    int m = blockIdx.x, t = threadIdx.x;
    const float* row = c + (size_t)m * 768;
    float v0 = row[t], v1 = row[t + 256], v2 = row[t + 512];
    __shared__ float red[4];
    float s = wave_red_sum(v0 + v1 + v2);
    if ((t & 63) == 0) red[t >> 6] = s;
    __syncthreads();
    float mean = (red[0] + red[1] + red[2] + red[3]) * (1.f / 768.f);
    __syncthreads();
    float d0 = v0 - mean, d1 = v1 - mean, d2 = v2 - mean;
    float q = wave_red_sum(d0 * d0 + d1 * d1 + d2 * d2);
    if ((t & 63) == 0) red[t >> 6] = q;
    __syncthreads();
    float inv = rsqrtf((red[0] + red[1] + red[2] + red[3]) * (1.f / 768.f) + 1e-7f);
    float* xr = x + (size_t)m * 768;
    xr[t] += d0 * inv * g[t] + bb[t];
    xr[t + 256] += d1 * inv * g[t + 256] + bb[t + 256];
    xr[t + 512] += d2 * inv * g[t + 512] + bb[t + 512];
}

__device__ __forceinline__ float fast_tanh(float z) {
    return 1.f - 2.f / (__expf(2.f * z) + 1.f);
}

// u (4096,4096) bf16: glu = a * gelu_tanh(gate); LN over 2048; -> h2 bf16 (4096,2048)
__global__ __launch_bounds__(256) void glu_ln(const u16* __restrict__ u, u16* __restrict__ h2) {
    int m = blockIdx.x, t = threadIdx.x;
    const u16* row = u + (size_t)m * 4096;
    float gv[8];
    float s = 0.f;
#pragma unroll
    for (int jj = 0; jj < 8; jj++) {
        int j = jj * 256 + t;
        float a = bf2f(row[j]);
        float gt = bf2f(row[2048 + j]);
        float ge = 0.5f * gt * (1.f + fast_tanh(0.7978845608028654f * (gt + 0.044715f * gt * gt * gt)));
        gv[jj] = a * ge;
        s += gv[jj];
    }
    __shared__ float red[4];
    s = wave_red_sum(s);
    if ((t & 63) == 0) red[t >> 6] = s;
    __syncthreads();
    float mean = (red[0] + red[1] + red[2] + red[3]) * (1.f / 2048.f);
    __syncthreads();
    float q2 = 0.f;
#pragma unroll
    for (int jj = 0; jj < 8; jj++) {
        float d = gv[jj] - mean;
        q2 += d * d;
    }
    q2 = wave_red_sum(q2);
    if ((t & 63) == 0) red[t >> 6] = q2;
    __syncthreads();
    float inv = rsqrtf((red[0] + red[1] + red[2] + red[3]) * (1.f / 2048.f) + 1e-7f);
    u16* out = h2 + (size_t)m * 2048;
#pragma unroll
    for (int jj = 0; jj < 8; jj++) out[jj * 256 + t] = f2bf((gv[jj] - mean) * inv);
}

// ---------------- GEMM 128x128: C[m,n] = sum_k A[m,k]*B[n,k] (+bias), bf16 MFMA ----------------
// modes: 1 = bf16 out, 5 = qkv scatter (out0=q,out1=k,out2=vT)
__global__ __launch_bounds__(256) void gemm_nt(const u16* __restrict__ A, const u16* __restrict__ B,
                                               const float* __restrict__ bias, int M, int N, int K,
                                               int mode, void* __restrict__ out0, void* __restrict__ out1,
                                               void* __restrict__ out2) {
    __shared__ __align__(16) u16 As[128 * 72];
    __shared__ __align__(16) u16 Bs[128 * 72];
    const int t = threadIdx.x;
    const int lane = t & 63, wave = t >> 6;
    const int wm = (wave >> 1) * 64, wn = (wave & 1) * 64;
    const int fr = lane & 15, qd = lane >> 4;
    const int m0 = blockIdx.y * 128, n0 = blockIdx.x * 128;
    const int row_s = t >> 3, g_s = t & 7;

    f32x4 zero4 = {0.f, 0.f, 0.f, 0.f};
    f32x4 acc[4][4];
#pragma unroll
    for (int i = 0; i < 4; i++)
#pragma unroll
        for (int j = 0; j < 4; j++) acc[i][j] = zero4;

    for (int k0 = 0; k0 < K; k0 += 64) {
        __syncthreads();
#pragma unroll
        for (int it = 0; it < 4; ++it) {
            int row = it * 32 + row_s;
            const float4* src = (const float4*)(A + (size_t)(m0 + row) * K + k0 + g_s * 8);
            *(float4*)&As[row * 72 + g_s * 8] = *src;
        }
#pragma unroll
        for (int it = 0; it < 4; ++it) {
            int row = it * 32 + row_s;
            const float4* src = (const float4*)(B + (size_t)(n0 + row) * K + k0 + g_s * 8);
            *(float4*)&Bs[row * 72 + g_s * 8] = *src;
        }
        __syncthreads();
#pragma unroll
        for (int s = 0; s < 2; ++s) {
            bf16x8 aF[4], bF[4];
#pragma unroll
            for (int i = 0; i < 4; i++) aF[i] = *(const bf16x8*)&As[(wm + i * 16 + fr) * 72 + s * 32 + qd * 8];
#pragma unroll
            for (int j = 0; j < 4; j++) bF[j] = *(const bf16x8*)&Bs[(wn + j * 16 + fr) * 72 + s * 32 + qd * 8];
#pragma unroll
            for (int i = 0; i < 4; i++)
#pragma unroll
                for (int j = 0; j < 4; j++)
                    acc[i][j] = __builtin_amdgcn_mfma_f32_16x16x32_bf16(aF[i], bF[j], acc[i][j], 0, 0, 0);
        }
    }

    // epilogue: D col = lane&15, row = (lane>>4)*4 + reg
#pragma unroll
    for (int j = 0; j < 4; j++) {
        int nn = n0 + wn + j * 16 + fr;
        float bval = bias ? bias[nn] : 0.f;
#pragma unroll
        for (int i = 0; i < 4; i++) {
#pragma unroll
            for (int rg = 0; rg < 4; ++rg) {
                int mm = m0 + wm + i * 16 + qd * 4 + rg;
                float val = acc[i][j][rg] + bval;
                if (mode == 1) {
                    ((u16*)out0)[(size_t)mm * N + nn] = f2bf(val);
                } else {  // mode 5: qkv scatter
                    int sidx = mm >> 3, bidx = mm & 7;
                    if (nn < 1536) {
                        int nn2 = nn;
                        u16* dst = (u16*)out0;
                        if (nn2 >= 768) { dst = (u16*)out1; nn2 -= 768; }
                        int hh = nn2 >> 6, dd = nn2 & 63;
                        dst[(size_t)((bidx * 12 + hh) * 512 + sidx) * 64 + dd] = f2bf(val);
                    } else {
                        int nn2 = nn - 1536;
                        int hh = nn2 >> 6, dd = nn2 & 63;
                        ((u16*)out2)[(size_t)((bidx * 12 + hh) * 64 + dd) * 512 + sidx] = f2bf(val);
                    }
                }
            }
        }
    }
}

// ---------------- GEMM 64x64, XCD-swizzled, for narrow-N GEMMs ----------------
// modes: 0 = fp32 out (+bias), 4 = fp32 residual +=
// grid: 1D, (M/64)*(N/64) blocks; requires (M/64) % 8 == 0.
__global__ __launch_bounds__(256) void gemm64(const u16* __restrict__ A, const u16* __restrict__ B,
                                              const float* __restrict__ bias, int M, int N, int K,
                                              int mode, float* __restrict__ out) {
    __shared__ __align__(16) u16 As[64 * 72];
    __shared__ __align__(16) u16 Bs[64 * 72];
    const int t = threadIdx.x;
    const int lane = t & 63, w = t >> 6;
    const int wm = (w >> 1) * 32, wn = (w & 1) * 32;
    const int fr = lane & 15, qd = lane >> 4;
    const int nt = N >> 6, mt = M >> 6;
    // XCD swizzle: consecutive ids round-robin XCDs; same-XCD ids sweep n fastest
    int lin = blockIdx.x;
    int c = lin & 7, s = lin >> 3;
    int m0 = (c * (mt >> 3) + s / nt) * 64;
    int n0 = (s % nt) * 64;
    const int rs = t >> 2, cs = (t & 3) * 16;

    f32x4 zero4 = {0.f, 0.f, 0.f, 0.f};
    f32x4 acc[2][2];
#pragma unroll
    for (int i = 0; i < 2; i++)
#pragma unroll
        for (int j = 0; j < 2; j++) acc[i][j] = zero4;

    for (int k0 = 0; k0 < K; k0 += 64) {
        __syncthreads();
        {
            const u16* ga = A + (size_t)(m0 + rs) * K + k0 + cs;
            *(float4*)&As[rs * 72 + cs] = *(const float4*)ga;
            *(float4*)&As[rs * 72 + cs + 8] = *(const float4*)(ga + 8);
            const u16* gb = B + (size_t)(n0 + rs) * K + k0 + cs;
            *(float4*)&Bs[rs * 72 + cs] = *(const float4*)gb;
            *(float4*)&Bs[rs * 72 + cs + 8] = *(const float4*)(gb + 8);
        }
        __syncthreads();
#pragma unroll
        for (int s2 = 0; s2 < 2; ++s2) {
            bf16x8 aF[2], bF[2];
#pragma unroll
            for (int i = 0; i < 2; i++) aF[i] = *(const bf16x8*)&As[(wm + i * 16 + fr) * 72 + s2 * 32 + qd * 8];
#pragma unroll
            for (int j = 0; j < 2; j++) bF[j] = *(const bf16x8*)&Bs[(wn + j * 16 + fr) * 72 + s2 * 32 + qd * 8];
#pragma unroll
            for (int i = 0; i < 2; i++)
#pragma unroll
                for (int j = 0; j < 2; j++)
                    acc[i][j] = __builtin_amdgcn_mfma_f32_16x16x32_bf16(aF[i], bF[j], acc[i][j], 0, 0, 0);
        }
    }

#pragma unroll
    for (int j = 0; j < 2; j++) {
        int nn = n0 + wn + j * 16 + fr;
        float bval = bias ? bias[nn] : 0.f;
#pragma unroll
        for (int i = 0; i < 2; i++) {
#pragma unroll
            for (int rg = 0; rg < 4; ++rg) {
                int mm = m0 + wm + i * 16 + qd * 4 + rg;
                float val = acc[i][j][rg] + bval;
                if (mode == 0)
                    out[(size_t)mm * N + nn] = val;
                else
                    out[(size_t)mm * N + nn] += val;
            }
        }
    }
}

// ---------------- position / attention ----------------

// pos = relpad @ Wqk_l^T + bqk_l for all 6 layers; rows 0..62 -> qposb/kposb per layer.
// grid: (24 n-tiles of 64, 6 layers), block 256
__global__ __launch_bounds__(256) void pos_mfma(const u16* __restrict__ relpad, const u16* __restrict__ wqkv_all,
                                                const float* __restrict__ bqkv_all, u16* __restrict__ qposb,
                                                u16* __restrict__ kposb) {
    __shared__ __align__(16) u16 As[64 * 72];
    __shared__ __align__(16) u16 Bs[64 * 72];
    int t = threadIdx.x, lane = t & 63, w = t >> 6;
    int fr = lane & 15, qd = lane >> 4;
    int n0 = blockIdx.x * 64, l = blockIdx.y;
    const u16* B = wqkv_all + (size_t)l * 2304 * 768;
    const float* bias = bqkv_all + (size_t)l * 2304;
    int rs = t >> 2, cs = (t & 3) * 16;
    f32x4 zero4 = {0.f, 0.f, 0.f, 0.f};
    f32x4 acc[4];
#pragma unroll
    for (int j = 0; j < 4; j++) acc[j] = zero4;

    for (int k0 = 0; k0 < 768; k0 += 64) {
        __syncthreads();
        const u16* ga = relpad + (size_t)rs * 768 + k0 + cs;
        *(float4*)&As[rs * 72 + cs] = *(const float4*)ga;
        *(float4*)&As[rs * 72 + cs + 8] = *(const float4*)(ga + 8);
        const u16* gb = B + (size_t)(n0 + rs) * 768 + k0 + cs;
        *(float4*)&Bs[rs * 72 + cs] = *(const float4*)gb;
        *(float4*)&Bs[rs * 72 + cs + 8] = *(const float4*)(gb + 8);
        __syncthreads();
#pragma unroll
        for (int s = 0; s < 2; s++) {
            bf16x8 aF = *(const bf16x8*)&As[(w * 16 + fr) * 72 + s * 32 + qd * 8];
#pragma unroll
            for (int jf = 0; jf < 4; jf++) {
                bf16x8 bF = *(const bf16x8*)&Bs[(jf * 16 + fr) * 72 + s * 32 + qd * 8];
                acc[jf] = __builtin_amdgcn_mfma_f32_16x16x32_bf16(aF, bF, acc[jf], 0, 0, 0);
            }
        }
    }
#pragma unroll
    for (int jf = 0; jf < 4; jf++) {
        int nn = n0 + jf * 16 + fr;
        float bval = bias[nn];
        int hh = nn >> 7, wd = nn & 127;
#pragma unroll
        for (int rg = 0; rg < 4; rg++) {
            int m = w * 16 + qd * 4 + rg;
            if (m >= 63) continue;
            float val = acc[jf][rg] + bval;
            size_t o = ((size_t)l * 12 + hh) * 64 * 64 + (size_t)m * 64;
            if (wd < 64) qposb[o + wd] = f2bf(val);
            else kposb[o + (wd - 64)] = f2bf(val);
        }
    }
}

// c2p[bh,s,j] = scale * q[bh,s,:].kpos[h,j,:];  p2c[bh,s,j] = scale * k[bh,s,:].qpos[h,j,:]  (bf16 out)
__global__ __launch_bounds__(256) void posdot_kernel(const u16* __restrict__ qbuf, const u16* __restrict__ kbuf,
                                                     const u16* __restrict__ qposb, const u16* __restrict__ kposb,
                                                     u16* __restrict__ c2pb, u16* __restrict__ p2cb) {
    __shared__ __align__(16) u16 Qs[128 * 72];
    __shared__ __align__(16) u16 Ks[128 * 72];
    __shared__ __align__(16) u16 QP[64 * 72];
    __shared__ __align__(16) u16 KP[64 * 72];
    const float scale = 0.07216878364870323f;  // 1/sqrt(192)
    int t = threadIdx.x, lane = t & 63, w = t >> 6;
    int fr = lane & 15, qd = lane >> 4;
    int s0 = blockIdx.x * 128, bh = blockIdx.y, h = bh % 12;
    size_t base = (size_t)bh * 512 * 64;
    {
        int rs = t >> 1, cs = (t & 1) * 32;
#pragma unroll
        for (int c = 0; c < 4; c++) {
            *(float4*)&Qs[rs * 72 + cs + c * 8] = *(const float4*)(qbuf + base + (size_t)(s0 + rs) * 64 + cs + c * 8);
            *(float4*)&Ks[rs * 72 + cs + c * 8] = *(const float4*)(kbuf + base + (size_t)(s0 + rs) * 64 + cs + c * 8);
        }
        int rs2 = t >> 2, cs2 = (t & 3) * 16;
        const u16* qp = qposb + (size_t)h * 64 * 64;
        const u16* kp = kposb + (size_t)h * 64 * 64;
#pragma unroll
        for (int c = 0; c < 2; c++) {
            *(float4*)&QP[rs2 * 72 + cs2 + c * 8] = *(const float4*)(qp + (size_t)rs2 * 64 + cs2 + c * 8);
            *(float4*)&KP[rs2 * 72 + cs2 + c * 8] = *(const float4*)(kp + (size_t)rs2 * 64 + cs2 + c * 8);
        }
    }
    __syncthreads();
    f32x4 zero4 = {0.f, 0.f, 0.f, 0.f};
    f32x4 cacc[2][4], pacc[2][4];
#pragma unroll
    for (int i = 0; i < 2; i++)
#pragma unroll
        for (int j = 0; j < 4; j++) { cacc[i][j] = zero4; pacc[i][j] = zero4; }
#pragma unroll
    for (int s = 0; s < 2; s++) {
#pragma unroll
        for (int i = 0; i < 2; i++) {
            bf16x8 aQ = *(const bf16x8*)&Qs[(w * 32 + i * 16 + fr) * 72 + s * 32 + qd * 8];
            bf16x8 aK = *(const bf16x8*)&Ks[(w * 32 + i * 16 + fr) * 72 + s * 32 + qd * 8];
#pragma unroll
            for (int jf = 0; jf < 4; jf++) {
                bf16x8 bKP = *(const bf16x8*)&KP[(jf * 16 + fr) * 72 + s * 32 + qd * 8];
                bf16x8 bQP = *(const bf16x8*)&QP[(jf * 16 + fr) * 72 + s * 32 + qd * 8];
                cacc[i][jf] = __builtin_amdgcn_mfma_f32_16x16x32_bf16(aQ, bKP, cacc[i][jf], 0, 0, 0);
                pacc[i][jf] = __builtin_amdgcn_mfma_f32_16x16x32_bf16(aK, bQP, pacc[i][jf], 0, 0, 0);
            }
        }
    }
#pragma unroll
    for (int i = 0; i < 2; i++)
#pragma unroll
        for (int jf = 0; jf < 4; jf++)
#pragma unroll
            for (int rg = 0; rg < 4; rg++) {
                int row = w * 32 + i * 16 + qd * 4 + rg;
                int col = jf * 16 + fr;
                size_t o = (size_t)(bh * 512 + s0 + row) * 64 + col;
                c2pb[o] = f2bf(cacc[i][jf][rg] * scale);
                p2cb[o] = f2bf(pacc[i][jf][rg] * scale);
            }
}

// fused flash attention with disentangled bias, MFMA.
// grid: (8 q-tiles of 64, 96 bh), block 256 (4 waves, 16 q-rows each)
// vbT layout: [bh][d][s] (pre-transposed). c2pb/p2cb bf16, pre-scaled.
__global__ __launch_bounds__(256) void attn_mfma(const u16* __restrict__ qbuf, const u16* __restrict__ kbuf,
                                                 const u16* __restrict__ vbT, const u16* __restrict__ c2pb,
                                                 const u16* __restrict__ p2cb, const unsigned char* __restrict__ diag8,
                                                 const unsigned char* __restrict__ mask, u16* __restrict__ ctxb) {
    __shared__ __align__(16) u16 Qs[64 * 72];
    __shared__ __align__(16) u16 KsPs[64 * 72];  // Ks during QK; per-wave Ps slices during PV
    __shared__ __align__(16) u16 Vt[64 * 72];    // [d][k]
    __shared__ __align__(16) u16 c2ps[64 * 72];  // [q][j]
    __shared__ __align__(16) u16 p2cs[64 * 72];  // [k][j]
    __shared__ unsigned char idxd[576];
    __shared__ unsigned char mks[512];
    const float scale = 0.07216878364870323f;  // 1/sqrt(192)
    int t = threadIdx.x, lane = t & 63, w = t >> 6;
    int fr = lane & 15, qd = lane >> 4;
    int qt = blockIdx.x, bh = blockIdx.y;
    int b = bh / 12, h = bh % 12;
    int q0 = qt * 64;
    size_t base = (size_t)bh * 512 * 64;
    int rs = t >> 2, cs = (t & 3) * 16;

    // stage Q tile, c2p rows, diag window, mask (once per block)
    {
        const u16* gq = qbuf + base + (size_t)(q0 + rs) * 64 + cs;
        *(float4*)&Qs[rs * 72 + cs] = *(const float4*)gq;
        *(float4*)&Qs[rs * 72 + cs + 8] = *(const float4*)(gq + 8);
        const u16* gc = c2pb + (size_t)(bh * 512 + q0 + rs) * 64 + cs;
        *(float4*)&c2ps[rs * 72 + cs] = *(const float4*)gc;
        *(float4*)&c2ps[rs * 72 + cs + 8] = *(const float4*)(gc + 8);
        for (int i = t; i < 575; i += 256) idxd[i] = diag8[q0 + i];
        for (int i = t; i < 512; i += 256) mks[i] = mask[b * 512 + i];
    }

    f32x4 zero4 = {0.f, 0.f, 0.f, 0.f};
    f32x4 oacc[4];
#pragma unroll
    for (int j = 0; j < 4; j++) oacc[j] = zero4;
    float m_i[4] = {-1e30f, -1e30f, -1e30f, -1e30f};
    float l_i[4] = {0.f, 0.f, 0.f, 0.f};
    const int ql0 = w * 16 + qd * 4;

    for (int kt = 0; kt < 8; kt++) {
        __syncthreads();
        {
            const u16* gk = kbuf + base + (size_t)(kt * 64 + rs) * 64 + cs;
            *(float4*)&KsPs[rs * 72 + cs] = *(const float4*)gk;
            *(float4*)&KsPs[rs * 72 + cs + 8] = *(const float4*)(gk + 8);
            const u16* gv = vbT + base + (size_t)rs * 512 + kt * 64 + cs;
            *(float4*)&Vt[rs * 72 + cs] = *(const float4*)gv;
            *(float4*)&Vt[rs * 72 + cs + 8] = *(const float4*)(gv + 8);
            const u16* gp = p2cb + (size_t)(bh * 512 + kt * 64 + rs) * 64 + cs;
            *(float4*)&p2cs[rs * 72 + cs] = *(const float4*)gp;
            *(float4*)&p2cs[rs * 72 + cs + 8] = *(const float4*)(gp + 8);
        }
        __syncthreads();

        // S = Q K^T
        f32x4 sacc[4];
#pragma unroll
        for (int j = 0; j < 4; j++) sacc[j] = zero4;
#pragma unroll
        for (int s = 0; s < 2; s++) {
            bf16x8 aQ = *(const bf16x8*)&Qs[(w * 16 + fr) * 72 + s * 32 + qd * 8];
#pragma unroll
            for (int jf = 0; jf < 4; jf++) {
                bf16x8 bK = *(const bf16x8*)&KsPs[(jf * 16 + fr) * 72 + s * 32 + qd * 8];
                sacc[jf] = __builtin_amdgcn_mfma_f32_16x16x32_bf16(aQ, bK, sacc[jf], 0, 0, 0);
            }
        }

        // bias + mask (all LDS)
        float pvv[4][4];
#pragma unroll
        for (int jf = 0; jf < 4; jf++) {
            int kl = jf * 16 + fr;
            int kg = kt * 64 + kl;
            bool mk = mks[kg] != 0;
#pragma unroll
            for (int rg = 0; rg < 4; rg++) {
                int ql = ql0 + rg;
                int j = idxd[ql - kg + 511];
                float bias = bf2f(c2ps[ql * 72 + j]) + bf2f(p2cs[kl * 72 + j]);
                float sval = sacc[jf][rg] * scale + bias;
                pvv[jf][rg] = mk ? -1e30f : sval;
            }
        }

        // online softmax per q-row (rows live across fr lanes)
#pragma unroll
        for (int rg = 0; rg < 4; rg++) {
            float rm = fmaxf(fmaxf(pvv[0][rg], pvv[1][rg]), fmaxf(pvv[2][rg], pvv[3][rg]));
#pragma unroll
            for (int msk = 1; msk < 16; msk <<= 1) rm = fmaxf(rm, __shfl_xor(rm, msk));
            float mnew = fmaxf(m_i[rg], rm);
            float alpha = __expf(m_i[rg] - mnew);
            m_i[rg] = mnew;
            float rsum = 0.f;
#pragma unroll
            for (int jf = 0; jf < 4; jf++) {
                float p = __expf(pvv[jf][rg] - mnew);
                pvv[jf][rg] = p;
                rsum += p;
            }
#pragma unroll
            for (int msk = 1; msk < 16; msk <<= 1) rsum += __shfl_xor(rsum, msk);
            l_i[rg] = l_i[rg] * alpha + rsum;
#pragma unroll
            for (int jf = 0; jf < 4; jf++) oacc[jf][rg] *= alpha;
        }

        __syncthreads();  // all waves done reading Ks before Ps overwrite

        // P -> LDS (A-operand relayout) into per-wave slice of KsPs
        u16* Psw = &KsPs[w * 16 * 72];
#pragma unroll
        for (int jf = 0; jf < 4; jf++)
#pragma unroll
            for (int rg = 0; rg < 4; rg++) Psw[(qd * 4 + rg) * 72 + jf * 16 + fr] = f2bf(pvv[jf][rg]);

        // O += P V
#pragma unroll
        for (int s = 0; s < 2; s++) {
            bf16x8 aP = *(const bf16x8*)&Psw[fr * 72 + s * 32 + qd * 8];
#pragma unroll
            for (int jf = 0; jf < 4; jf++) {
                bf16x8 bV = *(const bf16x8*)&Vt[(jf * 16 + fr) * 72 + s * 32 + qd * 8];
                oacc[jf] = __builtin_amdgcn_mfma_f32_16x16x32_bf16(aP, bV, oacc[jf], 0, 0, 0);
            }
        }
    }

    // epilogue
#pragma unroll
    for (int jf = 0; jf < 4; jf++) {
#pragma unroll
        for (int rg = 0; rg < 4; rg++) {
            int qg = q0 + ql0 + rg;
            int d = jf * 16 + fr;
            float o = oacc[jf][rg] / l_i[rg];
            int m = qg * 8 + b;
            ctxb[(size_t)m * 768 + h * 64 + d] = f2bf(o);
        }
    }
}

// ---------------- host ----------------

extern "C" void kernel_launch(void* const* d_in, const int* in_sizes, int n_in, void* d_out, int out_size,
                              void* d_ws, size_t ws_size, hipStream_t stream) {
    const float* hidden = (const float*)d_in[0];
    const unsigned char* mask = (const unsigned char*)d_in[1];
    const float* relemb = (const float*)d_in[2];
    const float* Wqk = (const float*)d_in[3];
    const float* bqk = (const float*)d_in[4];
    const float* Wv = (const float*)d_in[5];
    const float* bv = (const float*)d_in[6];
    const float* Wo = (const float*)d_in[7];
    const float* bo = (const float*)d_in[8];
    const float* lng = (const float*)d_in[9];
    const float* lnb = (const float*)d_in[10];
    const float* W1 = (const float*)d_in[11];
    const float* W2 = (const float*)d_in[12];
    float* x = (float*)d_out;

    char* wsp = (char*)d_ws;
    auto alloc = [&](size_t bytes) -> char* {
        char* p = wsp;
        wsp += (bytes + 255) & ~(size_t)255;
        return p;
    };
    u16* wqkv_bf = (u16*)alloc(6ull * 2304 * 768 * 2);
    float* bqkv = (float*)alloc(6ull * 2304 * 4);
    u16* wo_bf = (u16*)alloc(6ull * 768 * 768 * 2);
    u16* w1_bf = (u16*)alloc(6ull * 4096 * 768 * 2);
    u16* w2_bf = (u16*)alloc(6ull * 768 * 2048 * 2);
    u16* h_bf = (u16*)alloc(4096ull * 768 * 2);
    u16* qb = (u16*)alloc(96ull * 512 * 64 * 2);
    u16* kb = (u16*)alloc(96ull * 512 * 64 * 2);
    u16* vbT = (u16*)alloc(96ull * 512 * 64 * 2);
    u16* qposb = (u16*)alloc(6ull * 12 * 64 * 64 * 2);
    u16* kposb = (u16*)alloc(6ull * 12 * 64 * 64 * 2);
    u16* relpad = (u16*)alloc(64ull * 768 * 2);
    u16* c2pb = (u16*)alloc(96ull * 512 * 64 * 2);
    u16* p2cb = (u16*)alloc(96ull * 512 * 64 * 2);
    unsigned char* diag8 = (unsigned char*)alloc(1024);
    u16* ctxb = (u16*)alloc(4096ull * 768 * 2);
    float* ctxproj = (float*)alloc(4096ull * 768 * 4);
    u16* ubuf = (u16*)alloc(4096ull * 4096 * 2);
    u16* h2 = (u16*)alloc(4096ull * 2048 * 2);
    (void)ws_size;
    (void)in_sizes;
    (void)n_in;
    (void)out_size;

    auto conv = [&](const float* in, u16* out, size_t n) {
        size_t blocks = (n + 255) / 256;
        if (blocks > 8192) blocks = 8192;
        convert_kernel<<<dim3((unsigned)blocks), dim3(256), 0, stream>>>(in, out, (int)n);
    };
    convert_qkv_kernel<<<dim3(8192), dim3(256), 0, stream>>>(Wqk, Wv, wqkv_bf);
    bias_qkv_kernel<<<dim3(54), dim3(256), 0, stream>>>(bqk, bv, bqkv);
    conv(Wo, wo_bf, 6ull * 768 * 768);
    conv(W1, w1_bf, 6ull * 4096 * 768);
    conv(W2, w2_bf, 6ull * 768 * 2048);
    copy_kernel<<<dim3(4096), dim3(256), 0, stream>>>(hidden, x, 4096 * 768);
    diag_kernel<<<dim3(4), dim3(256), 0, stream>>>(diag8);
    relpad_kernel<<<dim3(192), dim3(256), 0, stream>>>(relemb, relpad);
    pos_mfma<<<dim3(24, 6), dim3(256), 0, stream>>>(relpad, wqkv_bf, bqkv, qposb, kposb);

    for (int l = 0; l < 6; l++) {
        ln_plain<<<dim3(4096), dim3(256), 0, stream>>>(x, h_bf);
        gemm_nt<<<dim3(18, 32), dim3(256), 0, stream>>>(h_bf, wqkv_bf + (size_t)l * 2304 * 768, bqkv + l * 2304,
                                                        4096, 2304, 768, 5, qb, kb, vbT);
        posdot_kernel<<<dim3(4, 96), dim3(256), 0, stream>>>(qb, kb, qposb + (size_t)l * 12 * 64 * 64,
                                                             kposb + (size_t)l * 12 * 64 * 64, c2pb, p2cb);
        attn_mfma<<<dim3(8, 96), dim3(256), 0, stream>>>(qb, kb, vbT, c2pb, p2cb, diag8, mask, ctxb);
        gemm64<<<dim3(768), dim3(256), 0, stream>>>(ctxb, wo_bf + (size_t)l * 768 * 768, bo + l * 768,
                                                    4096, 768, 768, 0, ctxproj);
        ln_res<<<dim3(4096), dim3(256), 0, stream>>>(ctxproj, lng + l * 768, lnb + l * 768, x);
        ln_plain<<<dim3(4096), dim3(256), 0, stream>>>(x, h_bf);
        gemm_nt<<<dim3(32, 32), dim3(256), 0, stream>>>(h_bf, w1_bf + (size_t)l * 4096 * 768, nullptr,
                                                        4096, 4096, 768, 1, ubuf, nullptr, nullptr);
        glu_ln<<<dim3(4096), dim3(256), 0, stream>>>(ubuf, h2);
        gemm64<<<dim3(768), dim3(256), 0, stream>>>(h2, w2_bf + (size_t)l * 768 * 2048, nullptr,
                                                    4096, 768, 2048, 4, x);
    }
}